// Round 1
// baseline (1684.673 us; speedup 1.0000x reference)
//
#include <hip/hip_runtime.h>
#include <hip/hip_bf16.h>

// Problem constants
// B=32, L=128, C=20, TOKEN_EMBED=300, CHAR_EMBED=50, NUM_FILTERS=200, KERNEL=3
// HID=256, LABELS=8, NS=6, D0=500, D1=512, BL=4096

typedef float floatx2 __attribute__((ext_vector_type(2)));
typedef short bf16x8 __attribute__((ext_vector_type(8)));
typedef float f32x4  __attribute__((ext_vector_type(4)));

__device__ __forceinline__ unsigned short f2bf(float x) {
    unsigned u = __float_as_uint(x);
    unsigned r = (u + 0x7fffu + ((u >> 16) & 1u)) >> 16;
    return (unsigned short)r;
}

// packed fp32 FMA with op_sel broadcast of h (low or high half of the pair)
__device__ __forceinline__ void pk_fma_bl(floatx2& acc, floatx2 w, floatx2 h) {
    asm("v_pk_fma_f32 %0, %1, %2, %0 op_sel_hi:[1,0,1]" : "+v"(acc) : "v"(w), "v"(h));
}
__device__ __forceinline__ void pk_fma_bh(floatx2& acc, floatx2 w, floatx2 h) {
    asm("v_pk_fma_f32 %0, %1, %2, %0 op_sel:[0,1,0]" : "+v"(acc) : "v"(w), "v"(h));
}

__device__ __forceinline__ float fsig(float x) {
    return __builtin_amdgcn_rcpf(1.f + __expf(-x));
}
__device__ __forceinline__ float ftanh(float x) {
    return fmaf(-2.f, __builtin_amdgcn_rcpf(1.f + __expf(2.f * x)), 1.f);
}

// 4 k-values (one uint4 of packed fp8 gate weights) x 4 gates = 16 MACs
__device__ __forceinline__ void dot4(floatx2& aif0, floatx2& ago0,
                                     floatx2& aif1, floatx2& ago1,
                                     uint4 w, const float* hsp, int k4) {
    float4 hv = *(const float4*)(hsp + k4 * 4);   // broadcast (same addr all lanes)
    floatx2 h01; h01.x = hv.x; h01.y = hv.y;
    floatx2 h23; h23.x = hv.z; h23.y = hv.w;
    floatx2 lo, hi;
    lo = __builtin_amdgcn_cvt_pk_f32_fp8((int)w.x, false);
    hi = __builtin_amdgcn_cvt_pk_f32_fp8((int)w.x, true);
    pk_fma_bl(aif0, lo, h01); pk_fma_bl(ago0, hi, h01);
    lo = __builtin_amdgcn_cvt_pk_f32_fp8((int)w.y, false);
    hi = __builtin_amdgcn_cvt_pk_f32_fp8((int)w.y, true);
    pk_fma_bh(aif0, lo, h01); pk_fma_bh(ago0, hi, h01);
    lo = __builtin_amdgcn_cvt_pk_f32_fp8((int)w.z, false);
    hi = __builtin_amdgcn_cvt_pk_f32_fp8((int)w.z, true);
    pk_fma_bl(aif1, lo, h23); pk_fma_bl(ago1, hi, h23);
    lo = __builtin_amdgcn_cvt_pk_f32_fp8((int)w.w, false);
    hi = __builtin_amdgcn_cvt_pk_f32_fp8((int)w.w, true);
    pk_fma_bh(aif1, lo, h23); pk_fma_bh(ago1, hi, h23);
}

// ---------------------------------------------------------------------------
// Prep: pack w_hh (both layers) to fp8 e4m3, now laid out as uint4 per
// (dir, k4, t): 4 consecutive k-values' packed (i,f,g,o) words. Also
// transpose crf_w / conv_w; zero d_out.
// ---------------------------------------------------------------------------
__global__ void prep(const float* __restrict__ wh0, const float* __restrict__ wh1,
                     const float* __restrict__ crf_w, const float* __restrict__ conv_w,
                     unsigned* __restrict__ Wp0, unsigned* __restrict__ Wp1,
                     float* __restrict__ crfBT, float* __restrict__ convWT,
                     float* __restrict__ outp)
{
    int idx = blockIdx.x * 256 + threadIdx.x;
    if (idx == 0) outp[0] = 0.f;
    const int NWP = 2 * 2 * 128 * 256;   // layer, dir, k2, t = 131072
    if (idx < NWP) {
        int layer = idx >> 16;
        int r     = idx & 65535;
        int dir   = r >> 15;
        int q     = r & 32767;
        int k2    = q >> 8;              // 0..127
        int t     = q & 255;
        const float* w = (layer ? wh1 : wh0) + dir * 1024 * 256;
        unsigned vx, vy;
        {
            int k = 2 * k2;
            float wi = w[(t      ) * 256 + k];
            float wf = w[(256 + t) * 256 + k];
            float wg = w[(512 + t) * 256 + k];
            float wo = w[(768 + t) * 256 + k];
            int u = __builtin_amdgcn_cvt_pk_fp8_f32(wi, wf, 0, false);
            u     = __builtin_amdgcn_cvt_pk_fp8_f32(wg, wo, u, true);
            vx = (unsigned)u;
        }
        {
            int k = 2 * k2 + 1;
            float wi = w[(t      ) * 256 + k];
            float wf = w[(256 + t) * 256 + k];
            float wg = w[(512 + t) * 256 + k];
            float wo = w[(768 + t) * 256 + k];
            int u = __builtin_amdgcn_cvt_pk_fp8_f32(wi, wf, 0, false);
            u     = __builtin_amdgcn_cvt_pk_fp8_f32(wg, wo, u, true);
            vy = (unsigned)u;
        }
        // uint4 entry e = (dir*64 + k4)*256 + t ; halves at +0/+2 uints
        unsigned* dst = layer ? Wp1 : Wp0;
        int k4 = k2 >> 1, half = k2 & 1;
        size_t e = ((((size_t)dir * 64 + k4) * 256) + t) * 4 + half * 2;
        dst[e]     = vx;
        dst[e + 1] = vy;
        return;
    }
    idx -= NWP;
    if (idx < 48 * 512) {
        int jj = idx >> 9, d = idx & 511;
        int kL = jj / 6, n = jj % 6;
        crfBT[idx] = crf_w[(kL * 512 + d) * 6 + n];
        return;
    }
    idx -= 48 * 512;
    if (idx < 30000) {
        int f = idx % 200, ek = idx / 200;
        int e = ek / 3, kk = ek % 3;
        convWT[idx] = conv_w[(f * 50 + e) * 3 + kk];
        return;
    }
}

// ---------------------------------------------------------------------------
// Embeddings + char conv + concat -> inp (4096 x 500)
// ---------------------------------------------------------------------------
__global__ __launch_bounds__(256) void embed_conv(
    const int* __restrict__ iv, const int* __restrict__ ov, const int* __restrict__ ch,
    const float* __restrict__ emb, const float* __restrict__ ooev, const float* __restrict__ ctab,
    const float* __restrict__ convWT, const float* __restrict__ convB,
    float* __restrict__ inp)
{
    const int bl = blockIdx.x;
    const int tid = threadIdx.x;
    __shared__ float sx[50 * 20];
    const int ivv = iv[bl];
    const int ovv = ov[bl];
    const float mo = (ovv != 0) ? 1.f : 0.f;
    for (int e = tid; e < 300; e += 256)
        inp[bl * 500 + e] = emb[(size_t)ivv * 300 + e] + mo * ooev[(size_t)ovv * 300 + e];
    for (int i = tid; i < 1000; i += 256) {
        int cI = i / 50, e = i % 50;
        int id = ch[bl * 20 + cI];
        sx[e * 20 + cI] = id ? ctab[id * 50 + e] : 0.f;
    }
    __syncthreads();
    if (tid < 200) {
        float acc[22];
        float bz = convB[tid];
        #pragma unroll
        for (int o = 0; o < 22; ++o) acc[o] = bz;
        for (int e = 0; e < 50; ++e) {
            float xr[20];
            #pragma unroll
            for (int q = 0; q < 5; ++q) {
                float4 v = *(const float4*)&sx[e * 20 + q * 4];
                xr[q * 4 + 0] = v.x; xr[q * 4 + 1] = v.y;
                xr[q * 4 + 2] = v.z; xr[q * 4 + 3] = v.w;
            }
            float w0 = convWT[(e * 3 + 0) * 200 + tid];
            float w1 = convWT[(e * 3 + 1) * 200 + tid];
            float w2 = convWT[(e * 3 + 2) * 200 + tid];
            #pragma unroll
            for (int o = 0; o < 22; ++o) {
                float s = acc[o];
                if (o >= 2)            s = fmaf(xr[o - 2], w0, s);
                if (o >= 1 && o <= 20) s = fmaf(xr[o - 1], w1, s);
                if (o <= 19)           s = fmaf(xr[o],     w2, s);
                acc[o] = s;
            }
        }
        float mx = acc[0];
        #pragma unroll
        for (int o = 1; o < 22; ++o) mx = fmaxf(mx, acc[o]);
        inp[bl * 500 + 300 + tid] = 1.f / (1.f + expf(-mx));
    }
}

// ---------------------------------------------------------------------------
// MFMA bf16 GEMM (verified correct: absmax 0.0)
// ---------------------------------------------------------------------------
__global__ __launch_bounds__(256) void gemm_mfma(
    const float* __restrict__ A, const float* __restrict__ Bm,
    const float* __restrict__ bias, float* __restrict__ C,
    int M, int N, int K)
{
    __shared__ unsigned short As[4][128][8];
    __shared__ unsigned short Bs[4][128][8];
    const int tid  = threadIdx.x;
    const int wave = tid >> 6, lane = tid & 63;
    const int quad = lane >> 4, lr = lane & 15;
    const int m0 = blockIdx.y * 128, n0 = blockIdx.x * 128;

    f32x4 acc[2][8];
    #pragma unroll
    for (int mt = 0; mt < 2; ++mt)
        #pragma unroll
        for (int nt = 0; nt < 8; ++nt) acc[mt][nt] = (f32x4){0.f, 0.f, 0.f, 0.f};

    const int ktiles = (K + 31) >> 5;
    for (int kt = 0; kt < ktiles; ++kt) {
        #pragma unroll
        for (int i = 0; i < 4; ++i) {
            int vid = tid + i * 256;
            int row = vid >> 3, kq = vid & 7;
            int kb  = kt * 32 + kq * 4;
            unsigned short ta[4], tb[4];
            const float* pa = A  + (size_t)(m0 + row) * K + kb;
            const float* pb = Bm + (size_t)(n0 + row) * K + kb;
            #pragma unroll
            for (int j = 0; j < 4; ++j) {
                ta[j] = (kb + j < K) ? f2bf(pa[j]) : (unsigned short)0;
                tb[j] = (kb + j < K) ? f2bf(pb[j]) : (unsigned short)0;
            }
            int ko = kq >> 1, jo = (kq & 1) * 4;
            *(ushort4*)&As[ko][row][jo] = make_ushort4(ta[0], ta[1], ta[2], ta[3]);
            *(ushort4*)&Bs[ko][row][jo] = make_ushort4(tb[0], tb[1], tb[2], tb[3]);
        }
        __syncthreads();
        bf16x8 bfr[8];
        #pragma unroll
        for (int nt = 0; nt < 8; ++nt)
            bfr[nt] = *(const bf16x8*)&Bs[quad][nt * 16 + lr][0];
        #pragma unroll
        for (int mt = 0; mt < 2; ++mt) {
            bf16x8 afr = *(const bf16x8*)&As[quad][wave * 32 + mt * 16 + lr][0];
            #pragma unroll
            for (int nt = 0; nt < 8; ++nt)
                acc[mt][nt] = __builtin_amdgcn_mfma_f32_16x16x32_bf16(
                    afr, bfr[nt], acc[mt][nt], 0, 0, 0);
        }
        __syncthreads();
    }
    #pragma unroll
    for (int mt = 0; mt < 2; ++mt)
        #pragma unroll
        for (int r = 0; r < 4; ++r) {
            int m = m0 + wave * 32 + mt * 16 + quad * 4 + r;
            #pragma unroll
            for (int nt = 0; nt < 8; ++nt) {
                int n = n0 + nt * 16 + lr;
                C[(size_t)m * N + n] = acc[mt][nt][r] + bias[n];
            }
        }
}

// ---------------------------------------------------------------------------
// fp32 GEMM (kept for the small emission GEMM, N=48)
// ---------------------------------------------------------------------------
__global__ __launch_bounds__(256) void gemm_bt(
    const float* __restrict__ A, const float* __restrict__ Bm,
    const float* __restrict__ bias, float* __restrict__ C,
    int M, int N, int K)
{
    __shared__ float At[16 * 128];
    __shared__ float Bt[16 * 128];
    const int tid = threadIdx.x;
    const int tx = tid & 15, ty = tid >> 4;
    const int m0 = blockIdx.y * 128, n0 = blockIdx.x * 128;
    float acc[2][2][4][4];
    #pragma unroll
    for (int a = 0; a < 2; ++a)
        #pragma unroll
        for (int b = 0; b < 2; ++b)
            #pragma unroll
            for (int i = 0; i < 4; ++i)
                #pragma unroll
                for (int j = 0; j < 4; ++j) acc[a][b][i][j] = 0.f;

    const int lr = tid >> 2;
    const int lc = (tid & 3) << 2;
    const int ktiles = (K + 15) >> 4;
    for (int kt = 0; kt < ktiles; ++kt) {
        const int k0 = kt << 4;
        #pragma unroll
        for (int half = 0; half < 2; ++half) {
            int r = lr + half * 64;
            int gk = k0 + lc;
            {
                int gm = m0 + r;
                float4 v = make_float4(0.f, 0.f, 0.f, 0.f);
                if (gm < M) {
                    const float* p = A + (size_t)gm * K + gk;
                    if (gk + 3 < K) v = *(const float4*)p;
                    else {
                        if (gk + 0 < K) v.x = p[0];
                        if (gk + 1 < K) v.y = p[1];
                        if (gk + 2 < K) v.z = p[2];
                        if (gk + 3 < K) v.w = p[3];
                    }
                }
                At[(lc + 0) * 128 + r] = v.x; At[(lc + 1) * 128 + r] = v.y;
                At[(lc + 2) * 128 + r] = v.z; At[(lc + 3) * 128 + r] = v.w;
            }
            {
                int gn = n0 + r;
                float4 v = make_float4(0.f, 0.f, 0.f, 0.f);
                if (gn < N) {
                    const float* p = Bm + (size_t)gn * K + gk;
                    if (gk + 3 < K) v = *(const float4*)p;
                    else {
                        if (gk + 0 < K) v.x = p[0];
                        if (gk + 1 < K) v.y = p[1];
                        if (gk + 2 < K) v.z = p[2];
                        if (gk + 3 < K) v.w = p[3];
                    }
                }
                Bt[(lc + 0) * 128 + r] = v.x; Bt[(lc + 1) * 128 + r] = v.y;
                Bt[(lc + 2) * 128 + r] = v.z; Bt[(lc + 3) * 128 + r] = v.w;
            }
        }
        __syncthreads();
        #pragma unroll
        for (int k = 0; k < 16; ++k) {
            float4 a0 = *(const float4*)&At[k * 128 + (ty << 2)];
            float4 a1 = *(const float4*)&At[k * 128 + 64 + (ty << 2)];
            float4 b0 = *(const float4*)&Bt[k * 128 + (tx << 2)];
            float4 b1 = *(const float4*)&Bt[k * 128 + 64 + (tx << 2)];
            float am[2][4] = {{a0.x, a0.y, a0.z, a0.w}, {a1.x, a1.y, a1.z, a1.w}};
            float bn[2][4] = {{b0.x, b0.y, b0.z, b0.w}, {b1.x, b1.y, b1.z, b1.w}};
            #pragma unroll
            for (int qa = 0; qa < 2; ++qa)
                #pragma unroll
                for (int qb = 0; qb < 2; ++qb)
                    #pragma unroll
                    for (int i = 0; i < 4; ++i)
                        #pragma unroll
                        for (int j = 0; j < 4; ++j)
                            acc[qa][qb][i][j] = fmaf(am[qa][i], bn[qb][j], acc[qa][qb][i][j]);
        }
        __syncthreads();
    }
    #pragma unroll
    for (int qa = 0; qa < 2; ++qa)
        #pragma unroll
        for (int i = 0; i < 4; ++i) {
            int m = m0 + qa * 64 + (ty << 2) + i;
            if (m >= M) continue;
            #pragma unroll
            for (int qb = 0; qb < 2; ++qb)
                #pragma unroll
                for (int j = 0; j < 4; ++j) {
                    int n = n0 + qb * 64 + (tx << 2) + j;
                    if (n < N) C[(size_t)m * N + n] = acc[qa][qb][i][j] + bias[n];
                }
        }
}

// ---------------------------------------------------------------------------
// LSTM recurrence v11: 1024 threads (16 waves = 4 waves/SIMD), 4-way k-split.
//  kh = tid>>8 in {0,1,2,3}; t = tid&255 owns one gate-quad output element.
//   kh0: k4 in [0,16)  from LDS  (+ gx loads + finalize -> lightest dot load)
//   kh1: k4 in [16,34) from LDS
//   kh2: k4 in [34,49) from REGISTERS (15 uint4 = 60 VGPR)
//   kh3: k4 in [49,64) from REGISTERS
// Weights pre-paired as uint4 (4 k-values) -> ds_read_b128 / 16B reg loads;
// h read as broadcast float4; MACs via v_pk_fma_f32 with op_sel broadcast
// (2 MACs/instr, no splat movs); dual accumulator pairs for ILP.
// LDS: 136 KB weights + 12 KB partials + 1.5 KB hs/msk = 149.5 KB.
// No streamed tail (all 64 k4-groups LDS- or register-resident).
// ---------------------------------------------------------------------------
#define L4LDS 34
#define K4REG 15
__global__ __launch_bounds__(1024) void lstm_rec(
    const float* __restrict__ xs, const uint4* __restrict__ Wp,
    const float* __restrict__ mask, float* __restrict__ out)
{
    const int tid = threadIdx.x;
    const int t   = tid & 255;
    const int kh  = tid >> 8;            // wave-uniform
    const int b   = blockIdx.x >> 1;
    const int dir = blockIdx.x & 1;
    __shared__ uint4 wlds[L4LDS * 256];          // 139264 B
    __shared__ float4 part[3 * 256];             // 12288 B
    __shared__ __align__(16) float hs[256];
    __shared__ float msk[128];

    const uint4* wp = Wp + (size_t)dir * 64 * 256;
    for (int j = tid; j < L4LDS * 256; j += 1024) wlds[j] = wp[j];
    uint4 wreg[K4REG];
    const int rbase = L4LDS + (kh - 2) * K4REG;  // 34 (kh2) / 49 (kh3)
    if (kh >= 2) {
        #pragma unroll
        for (int j = 0; j < K4REG; ++j) wreg[j] = wp[(rbase + j) * 256 + t];
    }
    if (tid < 256) hs[tid] = 0.f;
    if (tid < 128) msk[tid] = mask[b * 128 + tid];
    __syncthreads();

    float h = 0.f, c = 0.f;                      // live on kh==0 (t-owners)
    for (int s = 0; s < 128; ++s) {
        const int l = dir ? (127 - s) : s;
        floatx2 aif0 = {0.f, 0.f}, ago0 = {0.f, 0.f};
        floatx2 aif1 = {0.f, 0.f}, ago1 = {0.f, 0.f};
        float gi, gf, gg2, go;
        if (kh == 0) {
            const float* gxp = xs + ((size_t)(b * 128 + l) * 2048 + dir * 1024 + t);
            gi = gxp[0]; gf = gxp[256]; gg2 = gxp[512]; go = gxp[768];
            #pragma unroll 4
            for (int k4 = 0; k4 < 16; ++k4)
                dot4(aif0, ago0, aif1, ago1, wlds[k4 * 256 + t], hs, k4);
        } else if (kh == 1) {
            #pragma unroll 3
            for (int k4 = 16; k4 < 34; ++k4)
                dot4(aif0, ago0, aif1, ago1, wlds[k4 * 256 + t], hs, k4);
        } else {
            #pragma unroll
            for (int j = 0; j < K4REG; ++j)
                dot4(aif0, ago0, aif1, ago1, wreg[j], hs, rbase + j);
        }
        floatx2 aif = aif0 + aif1;
        floatx2 ago = ago0 + ago1;
        if (kh != 0)
            part[(kh - 1) * 256 + t] = make_float4(aif.x, aif.y, ago.x, ago.y);
        __syncthreads();                 // partials written; hs reads done
        if (kh == 0) {
            float4 p0 = part[t], p1 = part[256 + t], p2 = part[512 + t];
            float sai = aif.x + gi  + p0.x + p1.x + p2.x;
            float saf = aif.y + gf  + p0.y + p1.y + p2.y;
            float sag = ago.x + gg2 + p0.z + p1.z + p2.z;
            float sao = ago.y + go  + p0.w + p1.w + p2.w;
            float ig = fsig(sai);
            float fg = fsig(saf);
            float og = fsig(sao);
            float gg = ftanh(sag);
            float cn = fmaf(fg, c, ig * gg);
            float hn = og * ftanh(cn);
            float m = msk[l];
            h = m * hn + (1.f - m) * h;
            c = m * cn + (1.f - m) * c;
            hs[t] = h;
            out[(size_t)(b * 128 + l) * 512 + dir * 256 + t] = h;
        }
        __syncthreads();                 // new hs visible for next step
    }
}
#undef L4LDS
#undef K4REG

// ---------------------------------------------------------------------------
// CRF loss: 8 blocks (one per label k), 192 threads = (b in 0..31, j in 0..5)
// ---------------------------------------------------------------------------
__global__ __launch_bounds__(192) void crf_loss(
    const float* __restrict__ em, const float* __restrict__ trans,
    const int* __restrict__ target, const float* __restrict__ mask,
    float* __restrict__ outp)
{
    const int k = blockIdx.x;
    const int tid = threadIdx.x;
    const int b = tid & 31;
    const int j = tid >> 5;
    __shared__ float T[36];
    __shared__ float As[32][6];
    __shared__ float red[192];
    if (tid < 36) T[tid] = trans[k * 36 + tid];
    __syncthreads();
    const int* tg = target + (k * 32 + b) * 128;
    float sc = 0.f;
    for (int l = j; l < 128; l += 6) {
        int y = tg[l];
        float m = mask[b * 128 + l];
        sc += m * em[(b * 128 + l) * 48 + k * 6 + y];
        if (l > 0) sc += m * T[tg[l - 1] * 6 + y];
    }
    red[tid] = sc;
    float a = em[(b * 128) * 48 + k * 6 + j];
    As[b][j] = a;
    __syncthreads();
    for (int l = 1; l < 128; ++l) {
        float e = em[(b * 128 + l) * 48 + k * 6 + j];
        float v0 = As[b][0] + T[0 * 6 + j];
        float v1 = As[b][1] + T[1 * 6 + j];
        float v2 = As[b][2] + T[2 * 6 + j];
        float v3 = As[b][3] + T[3 * 6 + j];
        float v4 = As[b][4] + T[4 * 6 + j];
        float v5 = As[b][5] + T[5 * 6 + j];
        float mx = fmaxf(fmaxf(fmaxf(v0, v1), fmaxf(v2, v3)), fmaxf(v4, v5));
        float ssum = expf(v0 - mx) + expf(v1 - mx) + expf(v2 - mx)
                   + expf(v3 - mx) + expf(v4 - mx) + expf(v5 - mx);
        float na = mx + logf(ssum) + e;
        float m = mask[b * 128 + l];
        a = m * na + (1.f - m) * a;
        __syncthreads();
        As[b][j] = a;
        __syncthreads();
    }
    if (j == 0) {
        float v0 = As[b][0], v1 = As[b][1], v2 = As[b][2];
        float v3 = As[b][3], v4 = As[b][4], v5 = As[b][5];
        float mx = fmaxf(fmaxf(fmaxf(v0, v1), fmaxf(v2, v3)), fmaxf(v4, v5));
        float ssum = expf(v0 - mx) + expf(v1 - mx) + expf(v2 - mx)
                   + expf(v3 - mx) + expf(v4 - mx) + expf(v5 - mx);
        float logZ = mx + logf(ssum);
        float scb = red[b] + red[b + 32] + red[b + 64] + red[b + 96] + red[b + 128] + red[b + 160];
        red[b] = logZ - scb;
    }
    __syncthreads();
    if (tid == 0) {
        float tot = 0.f;
        for (int bb = 0; bb < 32; ++bb) tot += red[bb];
        atomicAdd(outp, tot * (1.f / 32.f));
    }
}

// ---------------------------------------------------------------------------
extern "C" void kernel_launch(void* const* d_in, const int* in_sizes, int n_in,
                              void* d_out, int out_size, void* d_ws, size_t ws_size,
                              hipStream_t stream)
{
    const int*   iv    = (const int*)d_in[0];
    const int*   ov    = (const int*)d_in[1];
    const int*   ch    = (const int*)d_in[2];
    const int*   tgt   = (const int*)d_in[3];
    const float* mask  = (const float*)d_in[4];
    const float* emb   = (const float*)d_in[5];
    const float* ooevT = (const float*)d_in[6];
    const float* ctab  = (const float*)d_in[7];
    const float* convW = (const float*)d_in[8];
    const float* convB = (const float*)d_in[9];
    const float* wih0  = (const float*)d_in[10];
    const float* whh0  = (const float*)d_in[11];
    const float* b0    = (const float*)d_in[12];
    const float* wih1  = (const float*)d_in[13];
    const float* whh1  = (const float*)d_in[14];
    const float* b1    = (const float*)d_in[15];
    const float* crfW  = (const float*)d_in[16];
    const float* crfB  = (const float*)d_in[17];
    const float* crfT  = (const float*)d_in[18];
    float* outp = (float*)d_out;

    char* ws = (char*)d_ws;
    size_t off = 0;
    auto alloc = [&](size_t bytes) {
        void* p = ws + off;
        off = (off + bytes + 255) & ~(size_t)255;
        return p;
    };
    float* inp    = (float*)alloc((size_t)4096 * 500 * 4);
    float* xs     = (float*)alloc((size_t)4096 * 2048 * 4);
    float* out0   = (float*)alloc((size_t)4096 * 512 * 4);
    float* out1   = (float*)alloc((size_t)4096 * 512 * 4);
    float* em     = (float*)alloc((size_t)4096 * 48 * 4);
    unsigned* Wp0 = (unsigned*)alloc((size_t)2 * 128 * 256 * 8);
    unsigned* Wp1 = (unsigned*)alloc((size_t)2 * 128 * 256 * 8);
    float* crfBT  = (float*)alloc((size_t)48 * 512 * 4);
    float* convWT = (float*)alloc((size_t)30000 * 4);

    const int prepN = 2 * 2 * 128 * 256 + 48 * 512 + 30000;
    prep<<<(prepN + 255) / 256, 256, 0, stream>>>(whh0, whh1, crfW, convW,
                                                  Wp0, Wp1, crfBT, convWT, outp);
    embed_conv<<<4096, 256, 0, stream>>>(iv, ov, ch, emb, ooevT, ctab, convWT, convB, inp);
    gemm_mfma<<<dim3(16, 32), 256, 0, stream>>>(inp, wih0, b0, xs, 4096, 2048, 500);
    lstm_rec<<<64, 1024, 0, stream>>>(xs, (const uint4*)Wp0, mask, out0);
    gemm_mfma<<<dim3(16, 32), 256, 0, stream>>>(out0, wih1, b1, xs, 4096, 2048, 512);
    lstm_rec<<<64, 1024, 0, stream>>>(xs, (const uint4*)Wp1, mask, out1);
    gemm_bt<<<dim3(1, 32), 256, 0, stream>>>(out1, crfBT, crfB, em, 4096, 48, 512);
    crf_loss<<<8, 192, 0, stream>>>(em, crfT, tgt, mask, outp);
}

// Round 2
// 1680.472 us; speedup vs baseline: 1.0025x; 1.0025x over previous
//
#include <hip/hip_runtime.h>
#include <hip/hip_bf16.h>

// Problem constants
// B=32, L=128, C=20, TOKEN_EMBED=300, CHAR_EMBED=50, NUM_FILTERS=200, KERNEL=3
// HID=256, LABELS=8, NS=6, D0=500, D1=512, BL=4096

typedef float floatx2 __attribute__((ext_vector_type(2)));
typedef short bf16x8 __attribute__((ext_vector_type(8)));
typedef float f32x4  __attribute__((ext_vector_type(4)));

__device__ __forceinline__ unsigned short f2bf(float x) {
    unsigned u = __float_as_uint(x);
    unsigned r = (u + 0x7fffu + ((u >> 16) & 1u)) >> 16;
    return (unsigned short)r;
}

// packed fp32 FMA with op_sel broadcast of h (low or high half of the pair)
__device__ __forceinline__ void pk_fma_bl(floatx2& acc, floatx2 w, floatx2 h) {
    asm("v_pk_fma_f32 %0, %1, %2, %0 op_sel_hi:[1,0,1]" : "+v"(acc) : "v"(w), "v"(h));
}
__device__ __forceinline__ void pk_fma_bh(floatx2& acc, floatx2 w, floatx2 h) {
    asm("v_pk_fma_f32 %0, %1, %2, %0 op_sel:[0,1,0]" : "+v"(acc) : "v"(w), "v"(h));
}

__device__ __forceinline__ float fsig(float x) {
    return __builtin_amdgcn_rcpf(1.f + __expf(-x));
}
__device__ __forceinline__ float ftanh(float x) {
    return fmaf(-2.f, __builtin_amdgcn_rcpf(1.f + __expf(2.f * x)), 1.f);
}

// 4 k-values (one uint4 of packed fp8 gate weights) x 4 gates = 16 MACs
__device__ __forceinline__ void dot4(floatx2& aif0, floatx2& ago0,
                                     floatx2& aif1, floatx2& ago1,
                                     uint4 w, const float* hsp, int k4) {
    float4 hv = *(const float4*)(hsp + k4 * 4);   // broadcast (same addr all lanes)
    floatx2 h01; h01.x = hv.x; h01.y = hv.y;
    floatx2 h23; h23.x = hv.z; h23.y = hv.w;
    floatx2 lo, hi;
    lo = __builtin_amdgcn_cvt_pk_f32_fp8((int)w.x, false);
    hi = __builtin_amdgcn_cvt_pk_f32_fp8((int)w.x, true);
    pk_fma_bl(aif0, lo, h01); pk_fma_bl(ago0, hi, h01);
    lo = __builtin_amdgcn_cvt_pk_f32_fp8((int)w.y, false);
    hi = __builtin_amdgcn_cvt_pk_f32_fp8((int)w.y, true);
    pk_fma_bh(aif0, lo, h01); pk_fma_bh(ago0, hi, h01);
    lo = __builtin_amdgcn_cvt_pk_f32_fp8((int)w.z, false);
    hi = __builtin_amdgcn_cvt_pk_f32_fp8((int)w.z, true);
    pk_fma_bl(aif1, lo, h23); pk_fma_bl(ago1, hi, h23);
    lo = __builtin_amdgcn_cvt_pk_f32_fp8((int)w.w, false);
    hi = __builtin_amdgcn_cvt_pk_f32_fp8((int)w.w, true);
    pk_fma_bh(aif1, lo, h23); pk_fma_bh(ago1, hi, h23);
}

// ---------------------------------------------------------------------------
// Prep: pack w_hh (both layers) to fp8 e4m3, laid out as uint4 per
// (dir, k4, t): 4 consecutive k-values' packed (i,f,g,o) words. Also
// transpose crf_w / conv_w; zero d_out.
// ---------------------------------------------------------------------------
__global__ void prep(const float* __restrict__ wh0, const float* __restrict__ wh1,
                     const float* __restrict__ crf_w, const float* __restrict__ conv_w,
                     unsigned* __restrict__ Wp0, unsigned* __restrict__ Wp1,
                     float* __restrict__ crfBT, float* __restrict__ convWT,
                     float* __restrict__ outp)
{
    int idx = blockIdx.x * 256 + threadIdx.x;
    if (idx == 0) outp[0] = 0.f;
    const int NWP = 2 * 2 * 128 * 256;   // layer, dir, k2, t = 131072
    if (idx < NWP) {
        int layer = idx >> 16;
        int r     = idx & 65535;
        int dir   = r >> 15;
        int q     = r & 32767;
        int k2    = q >> 8;              // 0..127
        int t     = q & 255;
        const float* w = (layer ? wh1 : wh0) + dir * 1024 * 256;
        unsigned vx, vy;
        {
            int k = 2 * k2;
            float wi = w[(t      ) * 256 + k];
            float wf = w[(256 + t) * 256 + k];
            float wg = w[(512 + t) * 256 + k];
            float wo = w[(768 + t) * 256 + k];
            int u = __builtin_amdgcn_cvt_pk_fp8_f32(wi, wf, 0, false);
            u     = __builtin_amdgcn_cvt_pk_fp8_f32(wg, wo, u, true);
            vx = (unsigned)u;
        }
        {
            int k = 2 * k2 + 1;
            float wi = w[(t      ) * 256 + k];
            float wf = w[(256 + t) * 256 + k];
            float wg = w[(512 + t) * 256 + k];
            float wo = w[(768 + t) * 256 + k];
            int u = __builtin_amdgcn_cvt_pk_fp8_f32(wi, wf, 0, false);
            u     = __builtin_amdgcn_cvt_pk_fp8_f32(wg, wo, u, true);
            vy = (unsigned)u;
        }
        // uint4 entry e = (dir*64 + k4)*256 + t ; halves at +0/+2 uints
        unsigned* dst = layer ? Wp1 : Wp0;
        int k4 = k2 >> 1, half = k2 & 1;
        size_t e = ((((size_t)dir * 64 + k4) * 256) + t) * 4 + half * 2;
        dst[e]     = vx;
        dst[e + 1] = vy;
        return;
    }
    idx -= NWP;
    if (idx < 48 * 512) {
        int jj = idx >> 9, d = idx & 511;
        int kL = jj / 6, n = jj % 6;
        crfBT[idx] = crf_w[(kL * 512 + d) * 6 + n];
        return;
    }
    idx -= 48 * 512;
    if (idx < 30000) {
        int f = idx % 200, ek = idx / 200;
        int e = ek / 3, kk = ek % 3;
        convWT[idx] = conv_w[(f * 50 + e) * 3 + kk];
        return;
    }
}

// ---------------------------------------------------------------------------
// Embeddings + char conv + concat -> inp (4096 x 500)
// ---------------------------------------------------------------------------
__global__ __launch_bounds__(256) void embed_conv(
    const int* __restrict__ iv, const int* __restrict__ ov, const int* __restrict__ ch,
    const float* __restrict__ emb, const float* __restrict__ ooev, const float* __restrict__ ctab,
    const float* __restrict__ convWT, const float* __restrict__ convB,
    float* __restrict__ inp)
{
    const int bl = blockIdx.x;
    const int tid = threadIdx.x;
    __shared__ float sx[50 * 20];
    const int ivv = iv[bl];
    const int ovv = ov[bl];
    const float mo = (ovv != 0) ? 1.f : 0.f;
    for (int e = tid; e < 300; e += 256)
        inp[bl * 500 + e] = emb[(size_t)ivv * 300 + e] + mo * ooev[(size_t)ovv * 300 + e];
    for (int i = tid; i < 1000; i += 256) {
        int cI = i / 50, e = i % 50;
        int id = ch[bl * 20 + cI];
        sx[e * 20 + cI] = id ? ctab[id * 50 + e] : 0.f;
    }
    __syncthreads();
    if (tid < 200) {
        float acc[22];
        float bz = convB[tid];
        #pragma unroll
        for (int o = 0; o < 22; ++o) acc[o] = bz;
        for (int e = 0; e < 50; ++e) {
            float xr[20];
            #pragma unroll
            for (int q = 0; q < 5; ++q) {
                float4 v = *(const float4*)&sx[e * 20 + q * 4];
                xr[q * 4 + 0] = v.x; xr[q * 4 + 1] = v.y;
                xr[q * 4 + 2] = v.z; xr[q * 4 + 3] = v.w;
            }
            float w0 = convWT[(e * 3 + 0) * 200 + tid];
            float w1 = convWT[(e * 3 + 1) * 200 + tid];
            float w2 = convWT[(e * 3 + 2) * 200 + tid];
            #pragma unroll
            for (int o = 0; o < 22; ++o) {
                float s = acc[o];
                if (o >= 2)            s = fmaf(xr[o - 2], w0, s);
                if (o >= 1 && o <= 20) s = fmaf(xr[o - 1], w1, s);
                if (o <= 19)           s = fmaf(xr[o],     w2, s);
                acc[o] = s;
            }
        }
        float mx = acc[0];
        #pragma unroll
        for (int o = 1; o < 22; ++o) mx = fmaxf(mx, acc[o]);
        inp[bl * 500 + 300 + tid] = 1.f / (1.f + expf(-mx));
    }
}

// ---------------------------------------------------------------------------
// MFMA bf16 GEMM (verified correct: absmax 0.0)
// ---------------------------------------------------------------------------
__global__ __launch_bounds__(256) void gemm_mfma(
    const float* __restrict__ A, const float* __restrict__ Bm,
    const float* __restrict__ bias, float* __restrict__ C,
    int M, int N, int K)
{
    __shared__ unsigned short As[4][128][8];
    __shared__ unsigned short Bs[4][128][8];
    const int tid  = threadIdx.x;
    const int wave = tid >> 6, lane = tid & 63;
    const int quad = lane >> 4, lr = lane & 15;
    const int m0 = blockIdx.y * 128, n0 = blockIdx.x * 128;

    f32x4 acc[2][8];
    #pragma unroll
    for (int mt = 0; mt < 2; ++mt)
        #pragma unroll
        for (int nt = 0; nt < 8; ++nt) acc[mt][nt] = (f32x4){0.f, 0.f, 0.f, 0.f};

    const int ktiles = (K + 31) >> 5;
    for (int kt = 0; kt < ktiles; ++kt) {
        #pragma unroll
        for (int i = 0; i < 4; ++i) {
            int vid = tid + i * 256;
            int row = vid >> 3, kq = vid & 7;
            int kb  = kt * 32 + kq * 4;
            unsigned short ta[4], tb[4];
            const float* pa = A  + (size_t)(m0 + row) * K + kb;
            const float* pb = Bm + (size_t)(n0 + row) * K + kb;
            #pragma unroll
            for (int j = 0; j < 4; ++j) {
                ta[j] = (kb + j < K) ? f2bf(pa[j]) : (unsigned short)0;
                tb[j] = (kb + j < K) ? f2bf(pb[j]) : (unsigned short)0;
            }
            int ko = kq >> 1, jo = (kq & 1) * 4;
            *(ushort4*)&As[ko][row][jo] = make_ushort4(ta[0], ta[1], ta[2], ta[3]);
            *(ushort4*)&Bs[ko][row][jo] = make_ushort4(tb[0], tb[1], tb[2], tb[3]);
        }
        __syncthreads();
        bf16x8 bfr[8];
        #pragma unroll
        for (int nt = 0; nt < 8; ++nt)
            bfr[nt] = *(const bf16x8*)&Bs[quad][nt * 16 + lr][0];
        #pragma unroll
        for (int mt = 0; mt < 2; ++mt) {
            bf16x8 afr = *(const bf16x8*)&As[quad][wave * 32 + mt * 16 + lr][0];
            #pragma unroll
            for (int nt = 0; nt < 8; ++nt)
                acc[mt][nt] = __builtin_amdgcn_mfma_f32_16x16x32_bf16(
                    afr, bfr[nt], acc[mt][nt], 0, 0, 0);
        }
        __syncthreads();
    }
    #pragma unroll
    for (int mt = 0; mt < 2; ++mt)
        #pragma unroll
        for (int r = 0; r < 4; ++r) {
            int m = m0 + wave * 32 + mt * 16 + quad * 4 + r;
            #pragma unroll
            for (int nt = 0; nt < 8; ++nt) {
                int n = n0 + nt * 16 + lr;
                C[(size_t)m * N + n] = acc[mt][nt][r] + bias[n];
            }
        }
}

// ---------------------------------------------------------------------------
// fp32 GEMM (kept for the small emission GEMM, N=48)
// ---------------------------------------------------------------------------
__global__ __launch_bounds__(256) void gemm_bt(
    const float* __restrict__ A, const float* __restrict__ Bm,
    const float* __restrict__ bias, float* __restrict__ C,
    int M, int N, int K)
{
    __shared__ float At[16 * 128];
    __shared__ float Bt[16 * 128];
    const int tid = threadIdx.x;
    const int tx = tid & 15, ty = tid >> 4;
    const int m0 = blockIdx.y * 128, n0 = blockIdx.x * 128;
    float acc[2][2][4][4];
    #pragma unroll
    for (int a = 0; a < 2; ++a)
        #pragma unroll
        for (int b = 0; b < 2; ++b)
            #pragma unroll
            for (int i = 0; i < 4; ++i)
                #pragma unroll
                for (int j = 0; j < 4; ++j) acc[a][b][i][j] = 0.f;

    const int lr = tid >> 2;
    const int lc = (tid & 3) << 2;
    const int ktiles = (K + 15) >> 4;
    for (int kt = 0; kt < ktiles; ++kt) {
        const int k0 = kt << 4;
        #pragma unroll
        for (int half = 0; half < 2; ++half) {
            int r = lr + half * 64;
            int gk = k0 + lc;
            {
                int gm = m0 + r;
                float4 v = make_float4(0.f, 0.f, 0.f, 0.f);
                if (gm < M) {
                    const float* p = A + (size_t)gm * K + gk;
                    if (gk + 3 < K) v = *(const float4*)p;
                    else {
                        if (gk + 0 < K) v.x = p[0];
                        if (gk + 1 < K) v.y = p[1];
                        if (gk + 2 < K) v.z = p[2];
                        if (gk + 3 < K) v.w = p[3];
                    }
                }
                At[(lc + 0) * 128 + r] = v.x; At[(lc + 1) * 128 + r] = v.y;
                At[(lc + 2) * 128 + r] = v.z; At[(lc + 3) * 128 + r] = v.w;
            }
            {
                int gn = n0 + r;
                float4 v = make_float4(0.f, 0.f, 0.f, 0.f);
                if (gn < N) {
                    const float* p = Bm + (size_t)gn * K + gk;
                    if (gk + 3 < K) v = *(const float4*)p;
                    else {
                        if (gk + 0 < K) v.x = p[0];
                        if (gk + 1 < K) v.y = p[1];
                        if (gk + 2 < K) v.z = p[2];
                        if (gk + 3 < K) v.w = p[3];
                    }
                }
                Bt[(lc + 0) * 128 + r] = v.x; Bt[(lc + 1) * 128 + r] = v.y;
                Bt[(lc + 2) * 128 + r] = v.z; Bt[(lc + 3) * 128 + r] = v.w;
            }
        }
        __syncthreads();
        #pragma unroll
        for (int k = 0; k < 16; ++k) {
            float4 a0 = *(const float4*)&At[k * 128 + (ty << 2)];
            float4 a1 = *(const float4*)&At[k * 128 + 64 + (ty << 2)];
            float4 b0 = *(const float4*)&Bt[k * 128 + (tx << 2)];
            float4 b1 = *(const float4*)&Bt[k * 128 + 64 + (tx << 2)];
            float am[2][4] = {{a0.x, a0.y, a0.z, a0.w}, {a1.x, a1.y, a1.z, a1.w}};
            float bn[2][4] = {{b0.x, b0.y, b0.z, b0.w}, {b1.x, b1.y, b1.z, b1.w}};
            #pragma unroll
            for (int qa = 0; qa < 2; ++qa)
                #pragma unroll
                for (int qb = 0; qb < 2; ++qb)
                    #pragma unroll
                    for (int i = 0; i < 4; ++i)
                        #pragma unroll
                        for (int j = 0; j < 4; ++j)
                            acc[qa][qb][i][j] = fmaf(am[qa][i], bn[qb][j], acc[qa][qb][i][j]);
        }
        __syncthreads();
    }
    #pragma unroll
    for (int qa = 0; qa < 2; ++qa)
        #pragma unroll
        for (int i = 0; i < 4; ++i) {
            int m = m0 + qa * 64 + (ty << 2) + i;
            if (m >= M) continue;
            #pragma unroll
            for (int qb = 0; qb < 2; ++qb)
                #pragma unroll
                for (int j = 0; j < 4; ++j) {
                    int n = n0 + qb * 64 + (tx << 2) + j;
                    if (n < N) C[(size_t)m * N + n] = acc[qa][qb][i][j] + bias[n];
                }
        }
}

// ---------------------------------------------------------------------------
// LSTM recurrence v12: same structure as v11 (1024 threads, 4-way k-split),
// but __launch_bounds__(1024, 4): LDS (149.5 KB) limits us to 1 block/CU =
// 4 waves/SIMD, so declare exactly that -> VGPR cap 128 (was 64, which
// spilled the 60-VGPR wreg array to scratch: WRITE_SIZE 8->19 MB, dur +18%).
//  kh = tid>>8 in {0,1,2,3}; t = tid&255 owns one gate-quad output element.
//   kh0: k4 in [0,16)  from LDS  (+ gx loads + finalize -> lightest dot load)
//   kh1: k4 in [16,34) from LDS
//   kh2: k4 in [34,49) from REGISTERS (15 uint4 = 60 VGPR)
//   kh3: k4 in [49,64) from REGISTERS
// LDS: 136 KB weights + 12 KB partials + 1.5 KB hs/msk = 149.5 KB.
// ---------------------------------------------------------------------------
#define L4LDS 34
#define K4REG 15
__global__ __launch_bounds__(1024, 4) void lstm_rec(
    const float* __restrict__ xs, const uint4* __restrict__ Wp,
    const float* __restrict__ mask, float* __restrict__ out)
{
    const int tid = threadIdx.x;
    const int t   = tid & 255;
    const int kh  = tid >> 8;            // wave-uniform
    const int b   = blockIdx.x >> 1;
    const int dir = blockIdx.x & 1;
    __shared__ uint4 wlds[L4LDS * 256];          // 139264 B
    __shared__ float4 part[3 * 256];             // 12288 B
    __shared__ __align__(16) float hs[256];
    __shared__ float msk[128];

    const uint4* wp = Wp + (size_t)dir * 64 * 256;
    for (int j = tid; j < L4LDS * 256; j += 1024) wlds[j] = wp[j];
    uint4 wreg[K4REG];
    const int rbase = L4LDS + (kh - 2) * K4REG;  // 34 (kh2) / 49 (kh3)
    if (kh >= 2) {
        #pragma unroll
        for (int j = 0; j < K4REG; ++j) wreg[j] = wp[(rbase + j) * 256 + t];
    }
    if (tid < 256) hs[tid] = 0.f;
    if (tid < 128) msk[tid] = mask[b * 128 + tid];
    __syncthreads();

    float h = 0.f, c = 0.f;                      // live on kh==0 (t-owners)
    for (int s = 0; s < 128; ++s) {
        const int l = dir ? (127 - s) : s;
        floatx2 aif0 = {0.f, 0.f}, ago0 = {0.f, 0.f};
        floatx2 aif1 = {0.f, 0.f}, ago1 = {0.f, 0.f};
        float gi, gf, gg2, go;
        if (kh == 0) {
            const float* gxp = xs + ((size_t)(b * 128 + l) * 2048 + dir * 1024 + t);
            gi = gxp[0]; gf = gxp[256]; gg2 = gxp[512]; go = gxp[768];
            #pragma unroll 4
            for (int k4 = 0; k4 < 16; ++k4)
                dot4(aif0, ago0, aif1, ago1, wlds[k4 * 256 + t], hs, k4);
        } else if (kh == 1) {
            #pragma unroll 3
            for (int k4 = 16; k4 < 34; ++k4)
                dot4(aif0, ago0, aif1, ago1, wlds[k4 * 256 + t], hs, k4);
        } else {
            #pragma unroll
            for (int j = 0; j < K4REG; ++j)
                dot4(aif0, ago0, aif1, ago1, wreg[j], hs, rbase + j);
        }
        floatx2 aif = aif0 + aif1;
        floatx2 ago = ago0 + ago1;
        if (kh != 0)
            part[(kh - 1) * 256 + t] = make_float4(aif.x, aif.y, ago.x, ago.y);
        __syncthreads();                 // partials written; hs reads done
        if (kh == 0) {
            float4 p0 = part[t], p1 = part[256 + t], p2 = part[512 + t];
            float sai = aif.x + gi  + p0.x + p1.x + p2.x;
            float saf = aif.y + gf  + p0.y + p1.y + p2.y;
            float sag = ago.x + gg2 + p0.z + p1.z + p2.z;
            float sao = ago.y + go  + p0.w + p1.w + p2.w;
            float ig = fsig(sai);
            float fg = fsig(saf);
            float og = fsig(sao);
            float gg = ftanh(sag);
            float cn = fmaf(fg, c, ig * gg);
            float hn = og * ftanh(cn);
            float m = msk[l];
            h = m * hn + (1.f - m) * h;
            c = m * cn + (1.f - m) * c;
            hs[t] = h;
            out[(size_t)(b * 128 + l) * 512 + dir * 256 + t] = h;
        }
        __syncthreads();                 // new hs visible for next step
    }
}
#undef L4LDS
#undef K4REG

// ---------------------------------------------------------------------------
// CRF loss: 8 blocks (one per label k), 192 threads = (b in 0..31, j in 0..5)
// ---------------------------------------------------------------------------
__global__ __launch_bounds__(192) void crf_loss(
    const float* __restrict__ em, const float* __restrict__ trans,
    const int* __restrict__ target, const float* __restrict__ mask,
    float* __restrict__ outp)
{
    const int k = blockIdx.x;
    const int tid = threadIdx.x;
    const int b = tid & 31;
    const int j = tid >> 5;
    __shared__ float T[36];
    __shared__ float As[32][6];
    __shared__ float red[192];
    if (tid < 36) T[tid] = trans[k * 36 + tid];
    __syncthreads();
    const int* tg = target + (k * 32 + b) * 128;
    float sc = 0.f;
    for (int l = j; l < 128; l += 6) {
        int y = tg[l];
        float m = mask[b * 128 + l];
        sc += m * em[(b * 128 + l) * 48 + k * 6 + y];
        if (l > 0) sc += m * T[tg[l - 1] * 6 + y];
    }
    red[tid] = sc;
    float a = em[(b * 128) * 48 + k * 6 + j];
    As[b][j] = a;
    __syncthreads();
    for (int l = 1; l < 128; ++l) {
        float e = em[(b * 128 + l) * 48 + k * 6 + j];
        float v0 = As[b][0] + T[0 * 6 + j];
        float v1 = As[b][1] + T[1 * 6 + j];
        float v2 = As[b][2] + T[2 * 6 + j];
        float v3 = As[b][3] + T[3 * 6 + j];
        float v4 = As[b][4] + T[4 * 6 + j];
        float v5 = As[b][5] + T[5 * 6 + j];
        float mx = fmaxf(fmaxf(fmaxf(v0, v1), fmaxf(v2, v3)), fmaxf(v4, v5));
        float ssum = expf(v0 - mx) + expf(v1 - mx) + expf(v2 - mx)
                   + expf(v3 - mx) + expf(v4 - mx) + expf(v5 - mx);
        float na = mx + logf(ssum) + e;
        float m = mask[b * 128 + l];
        a = m * na + (1.f - m) * a;
        __syncthreads();
        As[b][j] = a;
        __syncthreads();
    }
    if (j == 0) {
        float v0 = As[b][0], v1 = As[b][1], v2 = As[b][2];
        float v3 = As[b][3], v4 = As[b][4], v5 = As[b][5];
        float mx = fmaxf(fmaxf(fmaxf(v0, v1), fmaxf(v2, v3)), fmaxf(v4, v5));
        float ssum = expf(v0 - mx) + expf(v1 - mx) + expf(v2 - mx)
                   + expf(v3 - mx) + expf(v4 - mx) + expf(v5 - mx);
        float logZ = mx + logf(ssum);
        float scb = red[b] + red[b + 32] + red[b + 64] + red[b + 96] + red[b + 128] + red[b + 160];
        red[b] = logZ - scb;
    }
    __syncthreads();
    if (tid == 0) {
        float tot = 0.f;
        for (int bb = 0; bb < 32; ++bb) tot += red[bb];
        atomicAdd(outp, tot * (1.f / 32.f));
    }
}

// ---------------------------------------------------------------------------
extern "C" void kernel_launch(void* const* d_in, const int* in_sizes, int n_in,
                              void* d_out, int out_size, void* d_ws, size_t ws_size,
                              hipStream_t stream)
{
    const int*   iv    = (const int*)d_in[0];
    const int*   ov    = (const int*)d_in[1];
    const int*   ch    = (const int*)d_in[2];
    const int*   tgt   = (const int*)d_in[3];
    const float* mask  = (const float*)d_in[4];
    const float* emb   = (const float*)d_in[5];
    const float* ooevT = (const float*)d_in[6];
    const float* ctab  = (const float*)d_in[7];
    const float* convW = (const float*)d_in[8];
    const float* convB = (const float*)d_in[9];
    const float* wih0  = (const float*)d_in[10];
    const float* whh0  = (const float*)d_in[11];
    const float* b0    = (const float*)d_in[12];
    const float* wih1  = (const float*)d_in[13];
    const float* whh1  = (const float*)d_in[14];
    const float* b1    = (const float*)d_in[15];
    const float* crfW  = (const float*)d_in[16];
    const float* crfB  = (const float*)d_in[17];
    const float* crfT  = (const float*)d_in[18];
    float* outp = (float*)d_out;

    char* ws = (char*)d_ws;
    size_t off = 0;
    auto alloc = [&](size_t bytes) {
        void* p = ws + off;
        off = (off + bytes + 255) & ~(size_t)255;
        return p;
    };
    float* inp    = (float*)alloc((size_t)4096 * 500 * 4);
    float* xs     = (float*)alloc((size_t)4096 * 2048 * 4);
    float* out0   = (float*)alloc((size_t)4096 * 512 * 4);
    float* out1   = (float*)alloc((size_t)4096 * 512 * 4);
    float* em     = (float*)alloc((size_t)4096 * 48 * 4);
    unsigned* Wp0 = (unsigned*)alloc((size_t)2 * 128 * 256 * 8);
    unsigned* Wp1 = (unsigned*)alloc((size_t)2 * 128 * 256 * 8);
    float* crfBT  = (float*)alloc((size_t)48 * 512 * 4);
    float* convWT = (float*)alloc((size_t)30000 * 4);

    const int prepN = 2 * 2 * 128 * 256 + 48 * 512 + 30000;
    prep<<<(prepN + 255) / 256, 256, 0, stream>>>(whh0, whh1, crfW, convW,
                                                  Wp0, Wp1, crfBT, convWT, outp);
    embed_conv<<<4096, 256, 0, stream>>>(iv, ov, ch, emb, ooevT, ctab, convWT, convB, inp);
    gemm_mfma<<<dim3(16, 32), 256, 0, stream>>>(inp, wih0, b0, xs, 4096, 2048, 500);
    lstm_rec<<<64, 1024, 0, stream>>>(xs, (const uint4*)Wp0, mask, out0);
    gemm_mfma<<<dim3(16, 32), 256, 0, stream>>>(out0, wih1, b1, xs, 4096, 2048, 512);
    lstm_rec<<<64, 1024, 0, stream>>>(xs, (const uint4*)Wp1, mask, out1);
    gemm_bt<<<dim3(1, 32), 256, 0, stream>>>(out1, crfBT, crfB, em, 4096, 48, 512);
    crf_loss<<<8, 192, 0, stream>>>(em, crfT, tgt, mask, outp);
}

// Round 3
// 1325.256 us; speedup vs baseline: 1.2712x; 1.2680x over previous
//
#include <hip/hip_runtime.h>
#include <hip/hip_bf16.h>

// Problem constants
// B=32, L=128, C=20, TOKEN_EMBED=300, CHAR_EMBED=50, NUM_FILTERS=200, KERNEL=3
// HID=256, LABELS=8, NS=6, D0=500, D1=512, BL=4096

typedef float floatx2 __attribute__((ext_vector_type(2)));
typedef short bf16x8 __attribute__((ext_vector_type(8)));
typedef float f32x4  __attribute__((ext_vector_type(4)));

__device__ __forceinline__ unsigned short f2bf(float x) {
    unsigned u = __float_as_uint(x);
    unsigned r = (u + 0x7fffu + ((u >> 16) & 1u)) >> 16;
    return (unsigned short)r;
}

// packed fp32 FMA with op_sel broadcast of h (low or high half of the pair)
__device__ __forceinline__ void pk_fma_bl(floatx2& acc, floatx2 w, floatx2 h) {
    asm("v_pk_fma_f32 %0, %1, %2, %0 op_sel_hi:[1,0,1]" : "+v"(acc) : "v"(w), "v"(h));
}
__device__ __forceinline__ void pk_fma_bh(floatx2& acc, floatx2 w, floatx2 h) {
    asm("v_pk_fma_f32 %0, %1, %2, %0 op_sel:[0,1,0]" : "+v"(acc) : "v"(w), "v"(h));
}

__device__ __forceinline__ float fsig(float x) {
    return __builtin_amdgcn_rcpf(1.f + __expf(-x));
}
__device__ __forceinline__ float ftanh(float x) {
    return fmaf(-2.f, __builtin_amdgcn_rcpf(1.f + __expf(2.f * x)), 1.f);
}

// 4 k-values (one uint4 of packed fp8 gate weights) x 4 gates = 16 MACs
__device__ __forceinline__ void dot4(floatx2& aif0, floatx2& ago0,
                                     floatx2& aif1, floatx2& ago1,
                                     uint4 w, const float* hsp, int k4) {
    float4 hv = *(const float4*)(hsp + k4 * 4);   // broadcast (same addr all lanes)
    floatx2 h01; h01.x = hv.x; h01.y = hv.y;
    floatx2 h23; h23.x = hv.z; h23.y = hv.w;
    floatx2 lo, hi;
    lo = __builtin_amdgcn_cvt_pk_f32_fp8((int)w.x, false);
    hi = __builtin_amdgcn_cvt_pk_f32_fp8((int)w.x, true);
    pk_fma_bl(aif0, lo, h01); pk_fma_bl(ago0, hi, h01);
    lo = __builtin_amdgcn_cvt_pk_f32_fp8((int)w.y, false);
    hi = __builtin_amdgcn_cvt_pk_f32_fp8((int)w.y, true);
    pk_fma_bh(aif0, lo, h01); pk_fma_bh(ago0, hi, h01);
    lo = __builtin_amdgcn_cvt_pk_f32_fp8((int)w.z, false);
    hi = __builtin_amdgcn_cvt_pk_f32_fp8((int)w.z, true);
    pk_fma_bl(aif1, lo, h23); pk_fma_bl(ago1, hi, h23);
    lo = __builtin_amdgcn_cvt_pk_f32_fp8((int)w.w, false);
    hi = __builtin_amdgcn_cvt_pk_f32_fp8((int)w.w, true);
    pk_fma_bh(aif1, lo, h23); pk_fma_bh(ago1, hi, h23);
}

// ---------------------------------------------------------------------------
// Prep: pack w_hh (both layers) to fp8 e4m3, laid out as uint4 per
// (dir, k4, t): 4 consecutive k-values' packed (i,f,g,o) words. Also
// transpose crf_w / conv_w; zero d_out.
// ---------------------------------------------------------------------------
__global__ void prep(const float* __restrict__ wh0, const float* __restrict__ wh1,
                     const float* __restrict__ crf_w, const float* __restrict__ conv_w,
                     unsigned* __restrict__ Wp0, unsigned* __restrict__ Wp1,
                     float* __restrict__ crfBT, float* __restrict__ convWT,
                     float* __restrict__ outp)
{
    int idx = blockIdx.x * 256 + threadIdx.x;
    if (idx == 0) outp[0] = 0.f;
    const int NWP = 2 * 2 * 128 * 256;   // layer, dir, k2, t = 131072
    if (idx < NWP) {
        int layer = idx >> 16;
        int r     = idx & 65535;
        int dir   = r >> 15;
        int q     = r & 32767;
        int k2    = q >> 8;              // 0..127
        int t     = q & 255;
        const float* w = (layer ? wh1 : wh0) + dir * 1024 * 256;
        unsigned vx, vy;
        {
            int k = 2 * k2;
            float wi = w[(t      ) * 256 + k];
            float wf = w[(256 + t) * 256 + k];
            float wg = w[(512 + t) * 256 + k];
            float wo = w[(768 + t) * 256 + k];
            int u = __builtin_amdgcn_cvt_pk_fp8_f32(wi, wf, 0, false);
            u     = __builtin_amdgcn_cvt_pk_fp8_f32(wg, wo, u, true);
            vx = (unsigned)u;
        }
        {
            int k = 2 * k2 + 1;
            float wi = w[(t      ) * 256 + k];
            float wf = w[(256 + t) * 256 + k];
            float wg = w[(512 + t) * 256 + k];
            float wo = w[(768 + t) * 256 + k];
            int u = __builtin_amdgcn_cvt_pk_fp8_f32(wi, wf, 0, false);
            u     = __builtin_amdgcn_cvt_pk_fp8_f32(wg, wo, u, true);
            vy = (unsigned)u;
        }
        // uint4 entry e = (dir*64 + k4)*256 + t ; halves at +0/+2 uints
        unsigned* dst = layer ? Wp1 : Wp0;
        int k4 = k2 >> 1, half = k2 & 1;
        size_t e = ((((size_t)dir * 64 + k4) * 256) + t) * 4 + half * 2;
        dst[e]     = vx;
        dst[e + 1] = vy;
        return;
    }
    idx -= NWP;
    if (idx < 48 * 512) {
        int jj = idx >> 9, d = idx & 511;
        int kL = jj / 6, n = jj % 6;
        crfBT[idx] = crf_w[(kL * 512 + d) * 6 + n];
        return;
    }
    idx -= 48 * 512;
    if (idx < 30000) {
        int f = idx % 200, ek = idx / 200;
        int e = ek / 3, kk = ek % 3;
        convWT[idx] = conv_w[(f * 50 + e) * 3 + kk];
        return;
    }
}

// ---------------------------------------------------------------------------
// Embeddings + char conv + concat -> inp (4096 x 500)
// ---------------------------------------------------------------------------
__global__ __launch_bounds__(256) void embed_conv(
    const int* __restrict__ iv, const int* __restrict__ ov, const int* __restrict__ ch,
    const float* __restrict__ emb, const float* __restrict__ ooev, const float* __restrict__ ctab,
    const float* __restrict__ convWT, const float* __restrict__ convB,
    float* __restrict__ inp)
{
    const int bl = blockIdx.x;
    const int tid = threadIdx.x;
    __shared__ float sx[50 * 20];
    const int ivv = iv[bl];
    const int ovv = ov[bl];
    const float mo = (ovv != 0) ? 1.f : 0.f;
    for (int e = tid; e < 300; e += 256)
        inp[bl * 500 + e] = emb[(size_t)ivv * 300 + e] + mo * ooev[(size_t)ovv * 300 + e];
    for (int i = tid; i < 1000; i += 256) {
        int cI = i / 50, e = i % 50;
        int id = ch[bl * 20 + cI];
        sx[e * 20 + cI] = id ? ctab[id * 50 + e] : 0.f;
    }
    __syncthreads();
    if (tid < 200) {
        float acc[22];
        float bz = convB[tid];
        #pragma unroll
        for (int o = 0; o < 22; ++o) acc[o] = bz;
        for (int e = 0; e < 50; ++e) {
            float xr[20];
            #pragma unroll
            for (int q = 0; q < 5; ++q) {
                float4 v = *(const float4*)&sx[e * 20 + q * 4];
                xr[q * 4 + 0] = v.x; xr[q * 4 + 1] = v.y;
                xr[q * 4 + 2] = v.z; xr[q * 4 + 3] = v.w;
            }
            float w0 = convWT[(e * 3 + 0) * 200 + tid];
            float w1 = convWT[(e * 3 + 1) * 200 + tid];
            float w2 = convWT[(e * 3 + 2) * 200 + tid];
            #pragma unroll
            for (int o = 0; o < 22; ++o) {
                float s = acc[o];
                if (o >= 2)            s = fmaf(xr[o - 2], w0, s);
                if (o >= 1 && o <= 20) s = fmaf(xr[o - 1], w1, s);
                if (o <= 19)           s = fmaf(xr[o],     w2, s);
                acc[o] = s;
            }
        }
        float mx = acc[0];
        #pragma unroll
        for (int o = 1; o < 22; ++o) mx = fmaxf(mx, acc[o]);
        inp[bl * 500 + 300 + tid] = 1.f / (1.f + expf(-mx));
    }
}

// ---------------------------------------------------------------------------
// MFMA bf16 GEMM (verified correct: absmax 0.0)
// ---------------------------------------------------------------------------
__global__ __launch_bounds__(256) void gemm_mfma(
    const float* __restrict__ A, const float* __restrict__ Bm,
    const float* __restrict__ bias, float* __restrict__ C,
    int M, int N, int K)
{
    __shared__ unsigned short As[4][128][8];
    __shared__ unsigned short Bs[4][128][8];
    const int tid  = threadIdx.x;
    const int wave = tid >> 6, lane = tid & 63;
    const int quad = lane >> 4, lr = lane & 15;
    const int m0 = blockIdx.y * 128, n0 = blockIdx.x * 128;

    f32x4 acc[2][8];
    #pragma unroll
    for (int mt = 0; mt < 2; ++mt)
        #pragma unroll
        for (int nt = 0; nt < 8; ++nt) acc[mt][nt] = (f32x4){0.f, 0.f, 0.f, 0.f};

    const int ktiles = (K + 31) >> 5;
    for (int kt = 0; kt < ktiles; ++kt) {
        #pragma unroll
        for (int i = 0; i < 4; ++i) {
            int vid = tid + i * 256;
            int row = vid >> 3, kq = vid & 7;
            int kb  = kt * 32 + kq * 4;
            unsigned short ta[4], tb[4];
            const float* pa = A  + (size_t)(m0 + row) * K + kb;
            const float* pb = Bm + (size_t)(n0 + row) * K + kb;
            #pragma unroll
            for (int j = 0; j < 4; ++j) {
                ta[j] = (kb + j < K) ? f2bf(pa[j]) : (unsigned short)0;
                tb[j] = (kb + j < K) ? f2bf(pb[j]) : (unsigned short)0;
            }
            int ko = kq >> 1, jo = (kq & 1) * 4;
            *(ushort4*)&As[ko][row][jo] = make_ushort4(ta[0], ta[1], ta[2], ta[3]);
            *(ushort4*)&Bs[ko][row][jo] = make_ushort4(tb[0], tb[1], tb[2], tb[3]);
        }
        __syncthreads();
        bf16x8 bfr[8];
        #pragma unroll
        for (int nt = 0; nt < 8; ++nt)
            bfr[nt] = *(const bf16x8*)&Bs[quad][nt * 16 + lr][0];
        #pragma unroll
        for (int mt = 0; mt < 2; ++mt) {
            bf16x8 afr = *(const bf16x8*)&As[quad][wave * 32 + mt * 16 + lr][0];
            #pragma unroll
            for (int nt = 0; nt < 8; ++nt)
                acc[mt][nt] = __builtin_amdgcn_mfma_f32_16x16x32_bf16(
                    afr, bfr[nt], acc[mt][nt], 0, 0, 0);
        }
        __syncthreads();
    }
    #pragma unroll
    for (int mt = 0; mt < 2; ++mt)
        #pragma unroll
        for (int r = 0; r < 4; ++r) {
            int m = m0 + wave * 32 + mt * 16 + quad * 4 + r;
            #pragma unroll
            for (int nt = 0; nt < 8; ++nt) {
                int n = n0 + nt * 16 + lr;
                C[(size_t)m * N + n] = acc[mt][nt][r] + bias[n];
            }
        }
}

// ---------------------------------------------------------------------------
// fp32 GEMM (kept for the small emission GEMM, N=48)
// ---------------------------------------------------------------------------
__global__ __launch_bounds__(256) void gemm_bt(
    const float* __restrict__ A, const float* __restrict__ Bm,
    const float* __restrict__ bias, float* __restrict__ C,
    int M, int N, int K)
{
    __shared__ float At[16 * 128];
    __shared__ float Bt[16 * 128];
    const int tid = threadIdx.x;
    const int tx = tid & 15, ty = tid >> 4;
    const int m0 = blockIdx.y * 128, n0 = blockIdx.x * 128;
    float acc[2][2][4][4];
    #pragma unroll
    for (int a = 0; a < 2; ++a)
        #pragma unroll
        for (int b = 0; b < 2; ++b)
            #pragma unroll
            for (int i = 0; i < 4; ++i)
                #pragma unroll
                for (int j = 0; j < 4; ++j) acc[a][b][i][j] = 0.f;

    const int lr = tid >> 2;
    const int lc = (tid & 3) << 2;
    const int ktiles = (K + 15) >> 4;
    for (int kt = 0; kt < ktiles; ++kt) {
        const int k0 = kt << 4;
        #pragma unroll
        for (int half = 0; half < 2; ++half) {
            int r = lr + half * 64;
            int gk = k0 + lc;
            {
                int gm = m0 + r;
                float4 v = make_float4(0.f, 0.f, 0.f, 0.f);
                if (gm < M) {
                    const float* p = A + (size_t)gm * K + gk;
                    if (gk + 3 < K) v = *(const float4*)p;
                    else {
                        if (gk + 0 < K) v.x = p[0];
                        if (gk + 1 < K) v.y = p[1];
                        if (gk + 2 < K) v.z = p[2];
                        if (gk + 3 < K) v.w = p[3];
                    }
                }
                At[(lc + 0) * 128 + r] = v.x; At[(lc + 1) * 128 + r] = v.y;
                At[(lc + 2) * 128 + r] = v.z; At[(lc + 3) * 128 + r] = v.w;
            }
            {
                int gn = n0 + r;
                float4 v = make_float4(0.f, 0.f, 0.f, 0.f);
                if (gn < N) {
                    const float* p = Bm + (size_t)gn * K + gk;
                    if (gk + 3 < K) v = *(const float4*)p;
                    else {
                        if (gk + 0 < K) v.x = p[0];
                        if (gk + 1 < K) v.y = p[1];
                        if (gk + 2 < K) v.z = p[2];
                        if (gk + 3 < K) v.w = p[3];
                    }
                }
                Bt[(lc + 0) * 128 + r] = v.x; Bt[(lc + 1) * 128 + r] = v.y;
                Bt[(lc + 2) * 128 + r] = v.z; Bt[(lc + 3) * 128 + r] = v.w;
            }
        }
        __syncthreads();
        #pragma unroll
        for (int k = 0; k < 16; ++k) {
            float4 a0 = *(const float4*)&At[k * 128 + (ty << 2)];
            float4 a1 = *(const float4*)&At[k * 128 + 64 + (ty << 2)];
            float4 b0 = *(const float4*)&Bt[k * 128 + (tx << 2)];
            float4 b1 = *(const float4*)&Bt[k * 128 + 64 + (tx << 2)];
            float am[2][4] = {{a0.x, a0.y, a0.z, a0.w}, {a1.x, a1.y, a1.z, a1.w}};
            float bn[2][4] = {{b0.x, b0.y, b0.z, b0.w}, {b1.x, b1.y, b1.z, b1.w}};
            #pragma unroll
            for (int qa = 0; qa < 2; ++qa)
                #pragma unroll
                for (int qb = 0; qb < 2; ++qb)
                    #pragma unroll
                    for (int i = 0; i < 4; ++i)
                        #pragma unroll
                        for (int j = 0; j < 4; ++j)
                            acc[qa][qb][i][j] = fmaf(am[qa][i], bn[qb][j], acc[qa][qb][i][j]);
        }
        __syncthreads();
    }
    #pragma unroll
    for (int qa = 0; qa < 2; ++qa)
        #pragma unroll
        for (int i = 0; i < 4; ++i) {
            int m = m0 + qa * 64 + (ty << 2) + i;
            if (m >= M) continue;
            #pragma unroll
            for (int qb = 0; qb < 2; ++qb)
                #pragma unroll
                for (int j = 0; j < 4; ++j) {
                    int n = n0 + qb * 64 + (tx << 2) + j;
                    if (n < N) C[(size_t)m * N + n] = acc[qa][qb][i][j] + bias[n];
                }
        }
}

// ---------------------------------------------------------------------------
// LSTM recurrence v13: 1024 threads, 4-way k-split, NO register-resident
// weights (v11/v12's 60-VGPR wreg spilled at the compiler's 64-VGPR target
// and the launch-bounds hint was not honored). All weights come from:
//   LDS: 36 k4-groups (147 KB)   +   streamed global (L2-resident): 28 groups
// Streamed region = 112 KB/dir shared by all 32 same-dir blocks -> L2 hit.
// Split (balanced ~16-18 group-equivalents per wave; each SIMD hosts one
// wave of each flavor -> streamer VMEM latency hides under LDS waves' VALU):
//   kh0: LDS k4 [0,13)   + gx loads + finalize + out store
//   kh1: LDS k4 [13,27)  + stream [36,40)
//   kh2: LDS k4 [27,36)  + stream [40,48)
//   kh3: stream [48,64)  (named quad buffers, 8-deep load pipeline)
// Max live regs ~56 < 64 -> no spill by construction.
// LDS: 147456 (w) + 12288 (part) + 1024 (hs) + 512 (msk) = 161280 B.
// ---------------------------------------------------------------------------
#define L4LDS 36
__global__ __launch_bounds__(1024) void lstm_rec(
    const float* __restrict__ xs, const uint4* __restrict__ Wp,
    const float* __restrict__ mask, float* __restrict__ out)
{
    const int tid = threadIdx.x;
    const int t   = tid & 255;
    const int kh  = tid >> 8;            // wave-uniform
    const int b   = blockIdx.x >> 1;
    const int dir = blockIdx.x & 1;
    __shared__ uint4 wlds[L4LDS * 256];          // 147456 B
    __shared__ float4 part[3 * 256];             // 12288 B
    __shared__ __align__(16) float hs[256];
    __shared__ float msk[128];

    const uint4* wp = Wp + (size_t)dir * 64 * 256;
    for (int j = tid; j < L4LDS * 256; j += 1024) wlds[j] = wp[j];
    if (tid < 256) hs[tid] = 0.f;
    if (tid < 128) msk[tid] = mask[b * 128 + tid];
    __syncthreads();

    const uint4* sp = wp + t;                    // streamed: sp[g*256]
    float h = 0.f, c = 0.f;                      // live on kh==0 (t-owners)
    for (int s = 0; s < 128; ++s) {
        const int l = dir ? (127 - s) : s;
        floatx2 aif0 = {0.f, 0.f}, ago0 = {0.f, 0.f};
        floatx2 aif1 = {0.f, 0.f}, ago1 = {0.f, 0.f};
        float gi, gf, gg2, go;
        if (kh == 0) {
            const float* gxp = xs + ((size_t)(b * 128 + l) * 2048 + dir * 1024 + t);
            gi = gxp[0]; gf = gxp[256]; gg2 = gxp[512]; go = gxp[768];
            #pragma unroll 4
            for (int k4 = 0; k4 < 13; ++k4)
                dot4(aif0, ago0, aif1, ago1, wlds[k4 * 256 + t], hs, k4);
        } else if (kh == 1) {
            // issue 4 stream loads early, cover with 14 LDS dot4s
            uint4 a0 = sp[36 * 256], a1 = sp[37 * 256];
            uint4 a2 = sp[38 * 256], a3 = sp[39 * 256];
            #pragma unroll 4
            for (int k4 = 13; k4 < 27; ++k4)
                dot4(aif0, ago0, aif1, ago1, wlds[k4 * 256 + t], hs, k4);
            dot4(aif0, ago0, aif1, ago1, a0, hs, 36);
            dot4(aif0, ago0, aif1, ago1, a1, hs, 37);
            dot4(aif0, ago0, aif1, ago1, a2, hs, 38);
            dot4(aif0, ago0, aif1, ago1, a3, hs, 39);
        } else if (kh == 2) {
            // issue 8 stream loads early, cover with 9 LDS dot4s
            uint4 a0 = sp[40 * 256], a1 = sp[41 * 256];
            uint4 a2 = sp[42 * 256], a3 = sp[43 * 256];
            uint4 b0 = sp[44 * 256], b1 = sp[45 * 256];
            uint4 b2 = sp[46 * 256], b3 = sp[47 * 256];
            #pragma unroll 3
            for (int k4 = 27; k4 < 36; ++k4)
                dot4(aif0, ago0, aif1, ago1, wlds[k4 * 256 + t], hs, k4);
            dot4(aif0, ago0, aif1, ago1, a0, hs, 40);
            dot4(aif0, ago0, aif1, ago1, a1, hs, 41);
            dot4(aif0, ago0, aif1, ago1, a2, hs, 42);
            dot4(aif0, ago0, aif1, ago1, a3, hs, 43);
            dot4(aif0, ago0, aif1, ago1, b0, hs, 44);
            dot4(aif0, ago0, aif1, ago1, b1, hs, 45);
            dot4(aif0, ago0, aif1, ago1, b2, hs, 46);
            dot4(aif0, ago0, aif1, ago1, b3, hs, 47);
        } else {
            // pure streamer: 16 groups, 8-deep pipelined named quads
            uint4 a0 = sp[48 * 256], a1 = sp[49 * 256];
            uint4 a2 = sp[50 * 256], a3 = sp[51 * 256];
            uint4 b0 = sp[52 * 256], b1 = sp[53 * 256];
            uint4 b2 = sp[54 * 256], b3 = sp[55 * 256];
            dot4(aif0, ago0, aif1, ago1, a0, hs, 48);
            dot4(aif0, ago0, aif1, ago1, a1, hs, 49);
            dot4(aif0, ago0, aif1, ago1, a2, hs, 50);
            dot4(aif0, ago0, aif1, ago1, a3, hs, 51);
            a0 = sp[56 * 256]; a1 = sp[57 * 256];
            a2 = sp[58 * 256]; a3 = sp[59 * 256];
            dot4(aif0, ago0, aif1, ago1, b0, hs, 52);
            dot4(aif0, ago0, aif1, ago1, b1, hs, 53);
            dot4(aif0, ago0, aif1, ago1, b2, hs, 54);
            dot4(aif0, ago0, aif1, ago1, b3, hs, 55);
            b0 = sp[60 * 256]; b1 = sp[61 * 256];
            b2 = sp[62 * 256]; b3 = sp[63 * 256];
            dot4(aif0, ago0, aif1, ago1, a0, hs, 56);
            dot4(aif0, ago0, aif1, ago1, a1, hs, 57);
            dot4(aif0, ago0, aif1, ago1, a2, hs, 58);
            dot4(aif0, ago0, aif1, ago1, a3, hs, 59);
            dot4(aif0, ago0, aif1, ago1, b0, hs, 60);
            dot4(aif0, ago0, aif1, ago1, b1, hs, 61);
            dot4(aif0, ago0, aif1, ago1, b2, hs, 62);
            dot4(aif0, ago0, aif1, ago1, b3, hs, 63);
        }
        floatx2 aif = aif0 + aif1;
        floatx2 ago = ago0 + ago1;
        if (kh != 0)
            part[(kh - 1) * 256 + t] = make_float4(aif.x, aif.y, ago.x, ago.y);
        __syncthreads();                 // partials written; hs reads done
        if (kh == 0) {
            float4 p0 = part[t], p1 = part[256 + t], p2 = part[512 + t];
            float sai = aif.x + gi  + p0.x + p1.x + p2.x;
            float saf = aif.y + gf  + p0.y + p1.y + p2.y;
            float sag = ago.x + gg2 + p0.z + p1.z + p2.z;
            float sao = ago.y + go  + p0.w + p1.w + p2.w;
            float ig = fsig(sai);
            float fg = fsig(saf);
            float og = fsig(sao);
            float gg = ftanh(sag);
            float cn = fmaf(fg, c, ig * gg);
            float hn = og * ftanh(cn);
            float m = msk[l];
            h = m * hn + (1.f - m) * h;
            c = m * cn + (1.f - m) * c;
            hs[t] = h;
            out[(size_t)(b * 128 + l) * 512 + dir * 256 + t] = h;
        }
        __syncthreads();                 // new hs visible for next step
    }
}
#undef L4LDS

// ---------------------------------------------------------------------------
// CRF loss: 8 blocks (one per label k), 192 threads = (b in 0..31, j in 0..5)
// ---------------------------------------------------------------------------
__global__ __launch_bounds__(192) void crf_loss(
    const float* __restrict__ em, const float* __restrict__ trans,
    const int* __restrict__ target, const float* __restrict__ mask,
    float* __restrict__ outp)
{
    const int k = blockIdx.x;
    const int tid = threadIdx.x;
    const int b = tid & 31;
    const int j = tid >> 5;
    __shared__ float T[36];
    __shared__ float As[32][6];
    __shared__ float red[192];
    if (tid < 36) T[tid] = trans[k * 36 + tid];
    __syncthreads();
    const int* tg = target + (k * 32 + b) * 128;
    float sc = 0.f;
    for (int l = j; l < 128; l += 6) {
        int y = tg[l];
        float m = mask[b * 128 + l];
        sc += m * em[(b * 128 + l) * 48 + k * 6 + y];
        if (l > 0) sc += m * T[tg[l - 1] * 6 + y];
    }
    red[tid] = sc;
    float a = em[(b * 128) * 48 + k * 6 + j];
    As[b][j] = a;
    __syncthreads();
    for (int l = 1; l < 128; ++l) {
        float e = em[(b * 128 + l) * 48 + k * 6 + j];
        float v0 = As[b][0] + T[0 * 6 + j];
        float v1 = As[b][1] + T[1 * 6 + j];
        float v2 = As[b][2] + T[2 * 6 + j];
        float v3 = As[b][3] + T[3 * 6 + j];
        float v4 = As[b][4] + T[4 * 6 + j];
        float v5 = As[b][5] + T[5 * 6 + j];
        float mx = fmaxf(fmaxf(fmaxf(v0, v1), fmaxf(v2, v3)), fmaxf(v4, v5));
        float ssum = expf(v0 - mx) + expf(v1 - mx) + expf(v2 - mx)
                   + expf(v3 - mx) + expf(v4 - mx) + expf(v5 - mx);
        float na = mx + logf(ssum) + e;
        float m = mask[b * 128 + l];
        a = m * na + (1.f - m) * a;
        __syncthreads();
        As[b][j] = a;
        __syncthreads();
    }
    if (j == 0) {
        float v0 = As[b][0], v1 = As[b][1], v2 = As[b][2];
        float v3 = As[b][3], v4 = As[b][4], v5 = As[b][5];
        float mx = fmaxf(fmaxf(fmaxf(v0, v1), fmaxf(v2, v3)), fmaxf(v4, v5));
        float ssum = expf(v0 - mx) + expf(v1 - mx) + expf(v2 - mx)
                   + expf(v3 - mx) + expf(v4 - mx) + expf(v5 - mx);
        float logZ = mx + logf(ssum);
        float scb = red[b] + red[b + 32] + red[b + 64] + red[b + 96] + red[b + 128] + red[b + 160];
        red[b] = logZ - scb;
    }
    __syncthreads();
    if (tid == 0) {
        float tot = 0.f;
        for (int bb = 0; bb < 32; ++bb) tot += red[bb];
        atomicAdd(outp, tot * (1.f / 32.f));
    }
}

// ---------------------------------------------------------------------------
extern "C" void kernel_launch(void* const* d_in, const int* in_sizes, int n_in,
                              void* d_out, int out_size, void* d_ws, size_t ws_size,
                              hipStream_t stream)
{
    const int*   iv    = (const int*)d_in[0];
    const int*   ov    = (const int*)d_in[1];
    const int*   ch    = (const int*)d_in[2];
    const int*   tgt   = (const int*)d_in[3];
    const float* mask  = (const float*)d_in[4];
    const float* emb   = (const float*)d_in[5];
    const float* ooevT = (const float*)d_in[6];
    const float* ctab  = (const float*)d_in[7];
    const float* convW = (const float*)d_in[8];
    const float* convB = (const float*)d_in[9];
    const float* wih0  = (const float*)d_in[10];
    const float* whh0  = (const float*)d_in[11];
    const float* b0    = (const float*)d_in[12];
    const float* wih1  = (const float*)d_in[13];
    const float* whh1  = (const float*)d_in[14];
    const float* b1    = (const float*)d_in[15];
    const float* crfW  = (const float*)d_in[16];
    const float* crfB  = (const float*)d_in[17];
    const float* crfT  = (const float*)d_in[18];
    float* outp = (float*)d_out;

    char* ws = (char*)d_ws;
    size_t off = 0;
    auto alloc = [&](size_t bytes) {
        void* p = ws + off;
        off = (off + bytes + 255) & ~(size_t)255;
        return p;
    };
    float* inp    = (float*)alloc((size_t)4096 * 500 * 4);
    float* xs     = (float*)alloc((size_t)4096 * 2048 * 4);
    float* out0   = (float*)alloc((size_t)4096 * 512 * 4);
    float* out1   = (float*)alloc((size_t)4096 * 512 * 4);
    float* em     = (float*)alloc((size_t)4096 * 48 * 4);
    unsigned* Wp0 = (unsigned*)alloc((size_t)2 * 128 * 256 * 8);
    unsigned* Wp1 = (unsigned*)alloc((size_t)2 * 128 * 256 * 8);
    float* crfBT  = (float*)alloc((size_t)48 * 512 * 4);
    float* convWT = (float*)alloc((size_t)30000 * 4);

    const int prepN = 2 * 2 * 128 * 256 + 48 * 512 + 30000;
    prep<<<(prepN + 255) / 256, 256, 0, stream>>>(whh0, whh1, crfW, convW,
                                                  Wp0, Wp1, crfBT, convWT, outp);
    embed_conv<<<4096, 256, 0, stream>>>(iv, ov, ch, emb, ooevT, ctab, convWT, convB, inp);
    gemm_mfma<<<dim3(16, 32), 256, 0, stream>>>(inp, wih0, b0, xs, 4096, 2048, 500);
    lstm_rec<<<64, 1024, 0, stream>>>(xs, (const uint4*)Wp0, mask, out0);
    gemm_mfma<<<dim3(16, 32), 256, 0, stream>>>(out0, wih1, b1, xs, 4096, 2048, 512);
    lstm_rec<<<64, 1024, 0, stream>>>(xs, (const uint4*)Wp1, mask, out1);
    gemm_bt<<<dim3(1, 32), 256, 0, stream>>>(out1, crfBT, crfB, em, 4096, 48, 512);
    crf_loss<<<8, 192, 0, stream>>>(em, crfT, tgt, mask, outp);
}

// Round 4
// 1188.421 us; speedup vs baseline: 1.4176x; 1.1151x over previous
//
#include <hip/hip_runtime.h>
#include <hip/hip_bf16.h>

// Problem constants
// B=32, L=128, C=20, TOKEN_EMBED=300, CHAR_EMBED=50, NUM_FILTERS=200, KERNEL=3
// HID=256, LABELS=8, NS=6, D0=500 (padded 512), D1=512, BL=4096

typedef float floatx2 __attribute__((ext_vector_type(2)));
typedef short bf16x8 __attribute__((ext_vector_type(8)));
typedef float f32x4  __attribute__((ext_vector_type(4)));

__device__ __forceinline__ unsigned short f2bf(float x) {
    unsigned u = __float_as_uint(x);
    unsigned r = (u + 0x7fffu + ((u >> 16) & 1u)) >> 16;
    return (unsigned short)r;
}

// packed fp32 FMA with op_sel broadcast of h (low or high half of the pair)
__device__ __forceinline__ void pk_fma_bl(floatx2& acc, floatx2 w, floatx2 h) {
    asm("v_pk_fma_f32 %0, %1, %2, %0 op_sel_hi:[1,0,1]" : "+v"(acc) : "v"(w), "v"(h));
}
__device__ __forceinline__ void pk_fma_bh(floatx2& acc, floatx2 w, floatx2 h) {
    asm("v_pk_fma_f32 %0, %1, %2, %0 op_sel:[0,1,0]" : "+v"(acc) : "v"(w), "v"(h));
}

__device__ __forceinline__ float fsig(float x) {
    return __builtin_amdgcn_rcpf(1.f + __expf(-x));
}
__device__ __forceinline__ float ftanh(float x) {
    return fmaf(-2.f, __builtin_amdgcn_rcpf(1.f + __expf(2.f * x)), 1.f);
}

// 4 k-values (one uint4 of packed fp8 gate weights) x 4 gates = 16 MACs
__device__ __forceinline__ void dot4(floatx2& aif0, floatx2& ago0,
                                     floatx2& aif1, floatx2& ago1,
                                     uint4 w, const float* hsp, int k4) {
    float4 hv = *(const float4*)(hsp + k4 * 4);   // broadcast (same addr all lanes)
    floatx2 h01; h01.x = hv.x; h01.y = hv.y;
    floatx2 h23; h23.x = hv.z; h23.y = hv.w;
    floatx2 lo, hi;
    lo = __builtin_amdgcn_cvt_pk_f32_fp8((int)w.x, false);
    hi = __builtin_amdgcn_cvt_pk_f32_fp8((int)w.x, true);
    pk_fma_bl(aif0, lo, h01); pk_fma_bl(ago0, hi, h01);
    lo = __builtin_amdgcn_cvt_pk_f32_fp8((int)w.y, false);
    hi = __builtin_amdgcn_cvt_pk_f32_fp8((int)w.y, true);
    pk_fma_bh(aif0, lo, h01); pk_fma_bh(ago0, hi, h01);
    lo = __builtin_amdgcn_cvt_pk_f32_fp8((int)w.z, false);
    hi = __builtin_amdgcn_cvt_pk_f32_fp8((int)w.z, true);
    pk_fma_bl(aif1, lo, h23); pk_fma_bl(ago1, hi, h23);
    lo = __builtin_amdgcn_cvt_pk_f32_fp8((int)w.w, false);
    hi = __builtin_amdgcn_cvt_pk_f32_fp8((int)w.w, true);
    pk_fma_bh(aif1, lo, h23); pk_fma_bh(ago1, hi, h23);
}

// ---------------------------------------------------------------------------
// prep_misc: elementwise preps (all coalesced):
//  - wih0 (2048x500 fp32) -> wbf0 (2048x512 bf16, zero-padded)
//  - wih1 (2048x512 fp32) -> wbf1 (2048x512 bf16)
//  - crf_w transpose -> crfBT ; conv_w transpose -> convWT ; outp zero
// ---------------------------------------------------------------------------
__global__ void prep_misc(const float* __restrict__ wih0, const float* __restrict__ wih1,
                          const float* __restrict__ crf_w, const float* __restrict__ conv_w,
                          unsigned short* __restrict__ wbf0, unsigned short* __restrict__ wbf1,
                          float* __restrict__ crfBT, float* __restrict__ convWT,
                          float* __restrict__ outp)
{
    int idx = blockIdx.x * 256 + threadIdx.x;
    if (idx == 0) outp[0] = 0.f;
    const int NW = 2048 * 512;
    if (idx < NW) {
        int n = idx >> 9, k = idx & 511;
        wbf0[idx] = (k < 500) ? f2bf(wih0[n * 500 + k]) : (unsigned short)0;
        return;
    }
    idx -= NW;
    if (idx < NW) {
        wbf1[idx] = f2bf(wih1[idx]);
        return;
    }
    idx -= NW;
    if (idx < 48 * 512) {
        int jj = idx >> 9, d = idx & 511;
        int kL = jj / 6, n = jj % 6;
        crfBT[idx] = crf_w[(kL * 512 + d) * 6 + n];
        return;
    }
    idx -= 48 * 512;
    if (idx < 30000) {
        int f = idx % 200, ek = idx / 200;
        int e = ek / 3, kk = ek % 3;
        convWT[idx] = conv_w[(f * 50 + e) * 3 + kk];
        return;
    }
}

// ---------------------------------------------------------------------------
// prep_whh: coalesced tile-transpose pack of w_hh -> fp8 uint4 per (dir,k4,t).
// 64 blocks: layer(2) x dir(2) x t-tile(4 of 64) x k-tile(4 of 64).
// Reads coalesced float4 rows into padded LDS; packs byte-identically to the
// old strided prep (verified layout: word j of uint4 = packed (i,f | g,o)
// for k = 4*k4+j).
// ---------------------------------------------------------------------------
__global__ __launch_bounds__(256) void prep_whh(
    const float* __restrict__ wh0, const float* __restrict__ wh1,
    uint4* __restrict__ Wp0, uint4* __restrict__ Wp1)
{
    const int bid   = blockIdx.x;
    const int layer = bid >> 5;
    const int dir   = (bid >> 4) & 1;
    const int tt    = (bid >> 2) & 3;
    const int ktile = bid & 3;
    const float* w = (layer ? wh1 : wh0) + dir * 1024 * 256;
    uint4* dst = layer ? Wp1 : Wp0;
    const int t0 = tt * 64, k0 = ktile * 64;
    __shared__ float sxw[4][64][65];
    const int tid = threadIdx.x;
    #pragma unroll
    for (int g = 0; g < 4; ++g)
        #pragma unroll
        for (int q = 0; q < 4; ++q) {
            int lin = q * 256 + tid;
            int tr = lin >> 4, kc = (lin & 15) * 4;
            float4 v = *(const float4*)&w[(g * 256 + t0 + tr) * 256 + k0 + kc];
            sxw[g][tr][kc + 0] = v.x; sxw[g][tr][kc + 1] = v.y;
            sxw[g][tr][kc + 2] = v.z; sxw[g][tr][kc + 3] = v.w;
        }
    __syncthreads();
    const int t = tid & 63, k4g = tid >> 6;
    #pragma unroll
    for (int q = 0; q < 4; ++q) {
        int k4l = k4g * 4 + q;           // 0..15
        unsigned wrd[4];
        #pragma unroll
        for (int j = 0; j < 4; ++j) {
            int kc = k4l * 4 + j;
            float wi = sxw[0][t][kc], wf = sxw[1][t][kc];
            float wg = sxw[2][t][kc], wo = sxw[3][t][kc];
            int u = __builtin_amdgcn_cvt_pk_fp8_f32(wi, wf, 0, false);
            u     = __builtin_amdgcn_cvt_pk_fp8_f32(wg, wo, u, true);
            wrd[j] = (unsigned)u;
        }
        int k4 = (k0 >> 2) + k4l;
        dst[((size_t)dir * 64 + k4) * 256 + (t0 + t)] =
            make_uint4(wrd[0], wrd[1], wrd[2], wrd[3]);
    }
}

// ---------------------------------------------------------------------------
// Embeddings + char conv + concat -> inp (4096 x 512 bf16, cols 500..511 = 0)
// ---------------------------------------------------------------------------
__global__ __launch_bounds__(256) void embed_conv(
    const int* __restrict__ iv, const int* __restrict__ ov, const int* __restrict__ ch,
    const float* __restrict__ emb, const float* __restrict__ ooev, const float* __restrict__ ctab,
    const float* __restrict__ convWT, const float* __restrict__ convB,
    unsigned short* __restrict__ inp)
{
    const int bl = blockIdx.x;
    const int tid = threadIdx.x;
    __shared__ float sx[50 * 20];
    const int ivv = iv[bl];
    const int ovv = ov[bl];
    const float mo = (ovv != 0) ? 1.f : 0.f;
    for (int e = tid; e < 300; e += 256)
        inp[bl * 512 + e] = f2bf(emb[(size_t)ivv * 300 + e] + mo * ooev[(size_t)ovv * 300 + e]);
    for (int i = tid; i < 1000; i += 256) {
        int cI = i / 50, e = i % 50;
        int id = ch[bl * 20 + cI];
        sx[e * 20 + cI] = id ? ctab[id * 50 + e] : 0.f;
    }
    if (tid >= 200 && tid < 212) inp[bl * 512 + 300 + tid] = 0;  // pad 500..511
    __syncthreads();
    if (tid < 200) {
        float acc[22];
        float bz = convB[tid];
        #pragma unroll
        for (int o = 0; o < 22; ++o) acc[o] = bz;
        for (int e = 0; e < 50; ++e) {
            float xr[20];
            #pragma unroll
            for (int q = 0; q < 5; ++q) {
                float4 v = *(const float4*)&sx[e * 20 + q * 4];
                xr[q * 4 + 0] = v.x; xr[q * 4 + 1] = v.y;
                xr[q * 4 + 2] = v.z; xr[q * 4 + 3] = v.w;
            }
            float w0 = convWT[(e * 3 + 0) * 200 + tid];
            float w1 = convWT[(e * 3 + 1) * 200 + tid];
            float w2 = convWT[(e * 3 + 2) * 200 + tid];
            #pragma unroll
            for (int o = 0; o < 22; ++o) {
                float s = acc[o];
                if (o >= 2)            s = fmaf(xr[o - 2], w0, s);
                if (o >= 1 && o <= 20) s = fmaf(xr[o - 1], w1, s);
                if (o <= 19)           s = fmaf(xr[o],     w2, s);
                acc[o] = s;
            }
        }
        float mx = acc[0];
        #pragma unroll
        for (int o = 1; o < 22; ++o) mx = fmaxf(mx, acc[o]);
        inp[bl * 512 + 300 + tid] = f2bf(1.f / (1.f + expf(-mx)));
    }
}

// ---------------------------------------------------------------------------
// Pure-bf16 MFMA GEMM: A (Mx512 bf16), B (Nx512 bf16, row=output col), K=512.
// Staging: 4x 16B vector loads + 4x ds_write_b128 per thread per K-tile
// (replaces 32 scalar loads + 128 VALU of f2bf). MFMA section identical to
// the verified gemm_mfma.
// ---------------------------------------------------------------------------
__global__ __launch_bounds__(256) void gemm_bf16(
    const unsigned short* __restrict__ A, const unsigned short* __restrict__ Bm,
    const float* __restrict__ bias, float* __restrict__ C, int N)
{
    __shared__ unsigned short As[4][128][8];
    __shared__ unsigned short Bs[4][128][8];
    const int tid  = threadIdx.x;
    const int wave = tid >> 6, lane = tid & 63;
    const int quad = lane >> 4, lr = lane & 15;
    const int m0 = blockIdx.y * 128, n0 = blockIdx.x * 128;

    f32x4 acc[2][8];
    #pragma unroll
    for (int mt = 0; mt < 2; ++mt)
        #pragma unroll
        for (int nt = 0; nt < 8; ++nt) acc[mt][nt] = (f32x4){0.f, 0.f, 0.f, 0.f};

    for (int kt = 0; kt < 16; ++kt) {
        #pragma unroll
        for (int p = 0; p < 2; ++p) {
            int lin = p * 256 + tid;
            int row = lin & 127, c = lin >> 7;     // c in 0..3 over both passes
            *(bf16x8*)&As[c][row][0] =
                *(const bf16x8*)&A[(size_t)(m0 + row) * 512 + kt * 32 + c * 8];
            *(bf16x8*)&Bs[c][row][0] =
                *(const bf16x8*)&Bm[(size_t)(n0 + row) * 512 + kt * 32 + c * 8];
        }
        __syncthreads();
        bf16x8 bfr[8];
        #pragma unroll
        for (int nt = 0; nt < 8; ++nt)
            bfr[nt] = *(const bf16x8*)&Bs[quad][nt * 16 + lr][0];
        #pragma unroll
        for (int mt = 0; mt < 2; ++mt) {
            bf16x8 afr = *(const bf16x8*)&As[quad][wave * 32 + mt * 16 + lr][0];
            #pragma unroll
            for (int nt = 0; nt < 8; ++nt)
                acc[mt][nt] = __builtin_amdgcn_mfma_f32_16x16x32_bf16(
                    afr, bfr[nt], acc[mt][nt], 0, 0, 0);
        }
        __syncthreads();
    }
    #pragma unroll
    for (int mt = 0; mt < 2; ++mt)
        #pragma unroll
        for (int r = 0; r < 4; ++r) {
            int m = m0 + wave * 32 + mt * 16 + quad * 4 + r;
            #pragma unroll
            for (int nt = 0; nt < 8; ++nt) {
                int n = n0 + nt * 16 + lr;
                C[(size_t)m * N + n] = acc[mt][nt][r] + bias[n];
            }
        }
}

// ---------------------------------------------------------------------------
// fp32 GEMM (kept for the small emission GEMM, N=48)
// ---------------------------------------------------------------------------
__global__ __launch_bounds__(256) void gemm_bt(
    const float* __restrict__ A, const float* __restrict__ Bm,
    const float* __restrict__ bias, float* __restrict__ C,
    int M, int N, int K)
{
    __shared__ float At[16 * 128];
    __shared__ float Bt[16 * 128];
    const int tid = threadIdx.x;
    const int tx = tid & 15, ty = tid >> 4;
    const int m0 = blockIdx.y * 128, n0 = blockIdx.x * 128;
    float acc[2][2][4][4];
    #pragma unroll
    for (int a = 0; a < 2; ++a)
        #pragma unroll
        for (int b = 0; b < 2; ++b)
            #pragma unroll
            for (int i = 0; i < 4; ++i)
                #pragma unroll
                for (int j = 0; j < 4; ++j) acc[a][b][i][j] = 0.f;

    const int lr = tid >> 2;
    const int lc = (tid & 3) << 2;
    const int ktiles = (K + 15) >> 4;
    for (int kt = 0; kt < ktiles; ++kt) {
        const int k0 = kt << 4;
        #pragma unroll
        for (int half = 0; half < 2; ++half) {
            int r = lr + half * 64;
            int gk = k0 + lc;
            {
                int gm = m0 + r;
                float4 v = make_float4(0.f, 0.f, 0.f, 0.f);
                if (gm < M) {
                    const float* p = A + (size_t)gm * K + gk;
                    if (gk + 3 < K) v = *(const float4*)p;
                    else {
                        if (gk + 0 < K) v.x = p[0];
                        if (gk + 1 < K) v.y = p[1];
                        if (gk + 2 < K) v.z = p[2];
                        if (gk + 3 < K) v.w = p[3];
                    }
                }
                At[(lc + 0) * 128 + r] = v.x; At[(lc + 1) * 128 + r] = v.y;
                At[(lc + 2) * 128 + r] = v.z; At[(lc + 3) * 128 + r] = v.w;
            }
            {
                int gn = n0 + r;
                float4 v = make_float4(0.f, 0.f, 0.f, 0.f);
                if (gn < N) {
                    const float* p = Bm + (size_t)gn * K + gk;
                    if (gk + 3 < K) v = *(const float4*)p;
                    else {
                        if (gk + 0 < K) v.x = p[0];
                        if (gk + 1 < K) v.y = p[1];
                        if (gk + 2 < K) v.z = p[2];
                        if (gk + 3 < K) v.w = p[3];
                    }
                }
                Bt[(lc + 0) * 128 + r] = v.x; Bt[(lc + 1) * 128 + r] = v.y;
                Bt[(lc + 2) * 128 + r] = v.z; Bt[(lc + 3) * 128 + r] = v.w;
            }
        }
        __syncthreads();
        #pragma unroll
        for (int k = 0; k < 16; ++k) {
            float4 a0 = *(const float4*)&At[k * 128 + (ty << 2)];
            float4 a1 = *(const float4*)&At[k * 128 + 64 + (ty << 2)];
            float4 b0 = *(const float4*)&Bt[k * 128 + (tx << 2)];
            float4 b1 = *(const float4*)&Bt[k * 128 + 64 + (tx << 2)];
            float am[2][4] = {{a0.x, a0.y, a0.z, a0.w}, {a1.x, a1.y, a1.z, a1.w}};
            float bn[2][4] = {{b0.x, b0.y, b0.z, b0.w}, {b1.x, b1.y, b1.z, b1.w}};
            #pragma unroll
            for (int qa = 0; qa < 2; ++qa)
                #pragma unroll
                for (int qb = 0; qb < 2; ++qb)
                    #pragma unroll
                    for (int i = 0; i < 4; ++i)
                        #pragma unroll
                        for (int j = 0; j < 4; ++j)
                            acc[qa][qb][i][j] = fmaf(am[qa][i], bn[qb][j], acc[qa][qb][i][j]);
        }
        __syncthreads();
    }
    #pragma unroll
    for (int qa = 0; qa < 2; ++qa)
        #pragma unroll
        for (int i = 0; i < 4; ++i) {
            int m = m0 + qa * 64 + (ty << 2) + i;
            if (m >= M) continue;
            #pragma unroll
            for (int qb = 0; qb < 2; ++qb)
                #pragma unroll
                for (int j = 0; j < 4; ++j) {
                    int n = n0 + qb * 64 + (tx << 2) + j;
                    if (n < N) C[(size_t)m * N + n] = acc[qa][qb][i][j] + bias[n];
                }
        }
}

// ---------------------------------------------------------------------------
// LSTM recurrence v13b: unchanged v13 structure (1024 threads, 4-way k-split,
// 36 LDS groups + 28 L2-streamed groups, no register-resident weights).
// Adds a bf16 copy of h (outb) for the next layer's GEMM (same f2bf rounding
// the GEMM staging used -> numerically identical pipeline).
// ---------------------------------------------------------------------------
#define L4LDS 36
__global__ __launch_bounds__(1024) void lstm_rec(
    const float* __restrict__ xs, const uint4* __restrict__ Wp,
    const float* __restrict__ mask, float* __restrict__ out,
    unsigned short* __restrict__ outb)
{
    const int tid = threadIdx.x;
    const int t   = tid & 255;
    const int kh  = tid >> 8;            // wave-uniform
    const int b   = blockIdx.x >> 1;
    const int dir = blockIdx.x & 1;
    __shared__ uint4 wlds[L4LDS * 256];          // 147456 B
    __shared__ float4 part[3 * 256];             // 12288 B
    __shared__ __align__(16) float hs[256];
    __shared__ float msk[128];

    const uint4* wp = Wp + (size_t)dir * 64 * 256;
    for (int j = tid; j < L4LDS * 256; j += 1024) wlds[j] = wp[j];
    if (tid < 256) hs[tid] = 0.f;
    if (tid < 128) msk[tid] = mask[b * 128 + tid];
    __syncthreads();

    const uint4* sp = wp + t;                    // streamed: sp[g*256]
    float h = 0.f, c = 0.f;                      // live on kh==0 (t-owners)
    for (int s = 0; s < 128; ++s) {
        const int l = dir ? (127 - s) : s;
        floatx2 aif0 = {0.f, 0.f}, ago0 = {0.f, 0.f};
        floatx2 aif1 = {0.f, 0.f}, ago1 = {0.f, 0.f};
        float gi, gf, gg2, go;
        if (kh == 0) {
            const float* gxp = xs + ((size_t)(b * 128 + l) * 2048 + dir * 1024 + t);
            gi = gxp[0]; gf = gxp[256]; gg2 = gxp[512]; go = gxp[768];
            #pragma unroll 4
            for (int k4 = 0; k4 < 13; ++k4)
                dot4(aif0, ago0, aif1, ago1, wlds[k4 * 256 + t], hs, k4);
        } else if (kh == 1) {
            uint4 a0 = sp[36 * 256], a1 = sp[37 * 256];
            uint4 a2 = sp[38 * 256], a3 = sp[39 * 256];
            #pragma unroll 4
            for (int k4 = 13; k4 < 27; ++k4)
                dot4(aif0, ago0, aif1, ago1, wlds[k4 * 256 + t], hs, k4);
            dot4(aif0, ago0, aif1, ago1, a0, hs, 36);
            dot4(aif0, ago0, aif1, ago1, a1, hs, 37);
            dot4(aif0, ago0, aif1, ago1, a2, hs, 38);
            dot4(aif0, ago0, aif1, ago1, a3, hs, 39);
        } else if (kh == 2) {
            uint4 a0 = sp[40 * 256], a1 = sp[41 * 256];
            uint4 a2 = sp[42 * 256], a3 = sp[43 * 256];
            uint4 b0 = sp[44 * 256], b1 = sp[45 * 256];
            uint4 b2 = sp[46 * 256], b3 = sp[47 * 256];
            #pragma unroll 3
            for (int k4 = 27; k4 < 36; ++k4)
                dot4(aif0, ago0, aif1, ago1, wlds[k4 * 256 + t], hs, k4);
            dot4(aif0, ago0, aif1, ago1, a0, hs, 40);
            dot4(aif0, ago0, aif1, ago1, a1, hs, 41);
            dot4(aif0, ago0, aif1, ago1, a2, hs, 42);
            dot4(aif0, ago0, aif1, ago1, a3, hs, 43);
            dot4(aif0, ago0, aif1, ago1, b0, hs, 44);
            dot4(aif0, ago0, aif1, ago1, b1, hs, 45);
            dot4(aif0, ago0, aif1, ago1, b2, hs, 46);
            dot4(aif0, ago0, aif1, ago1, b3, hs, 47);
        } else {
            uint4 a0 = sp[48 * 256], a1 = sp[49 * 256];
            uint4 a2 = sp[50 * 256], a3 = sp[51 * 256];
            uint4 b0 = sp[52 * 256], b1 = sp[53 * 256];
            uint4 b2 = sp[54 * 256], b3 = sp[55 * 256];
            dot4(aif0, ago0, aif1, ago1, a0, hs, 48);
            dot4(aif0, ago0, aif1, ago1, a1, hs, 49);
            dot4(aif0, ago0, aif1, ago1, a2, hs, 50);
            dot4(aif0, ago0, aif1, ago1, a3, hs, 51);
            a0 = sp[56 * 256]; a1 = sp[57 * 256];
            a2 = sp[58 * 256]; a3 = sp[59 * 256];
            dot4(aif0, ago0, aif1, ago1, b0, hs, 52);
            dot4(aif0, ago0, aif1, ago1, b1, hs, 53);
            dot4(aif0, ago0, aif1, ago1, b2, hs, 54);
            dot4(aif0, ago0, aif1, ago1, b3, hs, 55);
            b0 = sp[60 * 256]; b1 = sp[61 * 256];
            b2 = sp[62 * 256]; b3 = sp[63 * 256];
            dot4(aif0, ago0, aif1, ago1, a0, hs, 56);
            dot4(aif0, ago0, aif1, ago1, a1, hs, 57);
            dot4(aif0, ago0, aif1, ago1, a2, hs, 58);
            dot4(aif0, ago0, aif1, ago1, a3, hs, 59);
            dot4(aif0, ago0, aif1, ago1, b0, hs, 60);
            dot4(aif0, ago0, aif1, ago1, b1, hs, 61);
            dot4(aif0, ago0, aif1, ago1, b2, hs, 62);
            dot4(aif0, ago0, aif1, ago1, b3, hs, 63);
        }
        floatx2 aif = aif0 + aif1;
        floatx2 ago = ago0 + ago1;
        if (kh != 0)
            part[(kh - 1) * 256 + t] = make_float4(aif.x, aif.y, ago.x, ago.y);
        __syncthreads();                 // partials written; hs reads done
        if (kh == 0) {
            float4 p0 = part[t], p1 = part[256 + t], p2 = part[512 + t];
            float sai = aif.x + gi  + p0.x + p1.x + p2.x;
            float saf = aif.y + gf  + p0.y + p1.y + p2.y;
            float sag = ago.x + gg2 + p0.z + p1.z + p2.z;
            float sao = ago.y + go  + p0.w + p1.w + p2.w;
            float ig = fsig(sai);
            float fg = fsig(saf);
            float og = fsig(sao);
            float gg = ftanh(sag);
            float cn = fmaf(fg, c, ig * gg);
            float hn = og * ftanh(cn);
            float m = msk[l];
            h = m * hn + (1.f - m) * h;
            c = m * cn + (1.f - m) * c;
            hs[t] = h;
            size_t oi = (size_t)(b * 128 + l) * 512 + dir * 256 + t;
            out[oi]  = h;
            outb[oi] = f2bf(h);
        }
        __syncthreads();                 // new hs visible for next step
    }
}
#undef L4LDS

// ---------------------------------------------------------------------------
// CRF loss: 8 blocks (one per label k), 192 threads = (b in 0..31, j in 0..5)
// ---------------------------------------------------------------------------
__global__ __launch_bounds__(192) void crf_loss(
    const float* __restrict__ em, const float* __restrict__ trans,
    const int* __restrict__ target, const float* __restrict__ mask,
    float* __restrict__ outp)
{
    const int k = blockIdx.x;
    const int tid = threadIdx.x;
    const int b = tid & 31;
    const int j = tid >> 5;
    __shared__ float T[36];
    __shared__ float As[32][6];
    __shared__ float red[192];
    if (tid < 36) T[tid] = trans[k * 36 + tid];
    __syncthreads();
    const int* tg = target + (k * 32 + b) * 128;
    float sc = 0.f;
    for (int l = j; l < 128; l += 6) {
        int y = tg[l];
        float m = mask[b * 128 + l];
        sc += m * em[(b * 128 + l) * 48 + k * 6 + y];
        if (l > 0) sc += m * T[tg[l - 1] * 6 + y];
    }
    red[tid] = sc;
    float a = em[(b * 128) * 48 + k * 6 + j];
    As[b][j] = a;
    __syncthreads();
    for (int l = 1; l < 128; ++l) {
        float e = em[(b * 128 + l) * 48 + k * 6 + j];
        float v0 = As[b][0] + T[0 * 6 + j];
        float v1 = As[b][1] + T[1 * 6 + j];
        float v2 = As[b][2] + T[2 * 6 + j];
        float v3 = As[b][3] + T[3 * 6 + j];
        float v4 = As[b][4] + T[4 * 6 + j];
        float v5 = As[b][5] + T[5 * 6 + j];
        float mx = fmaxf(fmaxf(fmaxf(v0, v1), fmaxf(v2, v3)), fmaxf(v4, v5));
        float ssum = expf(v0 - mx) + expf(v1 - mx) + expf(v2 - mx)
                   + expf(v3 - mx) + expf(v4 - mx) + expf(v5 - mx);
        float na = mx + logf(ssum) + e;
        float m = mask[b * 128 + l];
        a = m * na + (1.f - m) * a;
        __syncthreads();
        As[b][j] = a;
        __syncthreads();
    }
    if (j == 0) {
        float v0 = As[b][0], v1 = As[b][1], v2 = As[b][2];
        float v3 = As[b][3], v4 = As[b][4], v5 = As[b][5];
        float mx = fmaxf(fmaxf(fmaxf(v0, v1), fmaxf(v2, v3)), fmaxf(v4, v5));
        float ssum = expf(v0 - mx) + expf(v1 - mx) + expf(v2 - mx)
                   + expf(v3 - mx) + expf(v4 - mx) + expf(v5 - mx);
        float logZ = mx + logf(ssum);
        float scb = red[b] + red[b + 32] + red[b + 64] + red[b + 96] + red[b + 128] + red[b + 160];
        red[b] = logZ - scb;
    }
    __syncthreads();
    if (tid == 0) {
        float tot = 0.f;
        for (int bb = 0; bb < 32; ++bb) tot += red[bb];
        atomicAdd(outp, tot * (1.f / 32.f));
    }
}

// ---------------------------------------------------------------------------
extern "C" void kernel_launch(void* const* d_in, const int* in_sizes, int n_in,
                              void* d_out, int out_size, void* d_ws, size_t ws_size,
                              hipStream_t stream)
{
    const int*   iv    = (const int*)d_in[0];
    const int*   ov    = (const int*)d_in[1];
    const int*   ch    = (const int*)d_in[2];
    const int*   tgt   = (const int*)d_in[3];
    const float* mask  = (const float*)d_in[4];
    const float* emb   = (const float*)d_in[5];
    const float* ooevT = (const float*)d_in[6];
    const float* ctab  = (const float*)d_in[7];
    const float* convW = (const float*)d_in[8];
    const float* convB = (const float*)d_in[9];
    const float* wih0  = (const float*)d_in[10];
    const float* whh0  = (const float*)d_in[11];
    const float* b0    = (const float*)d_in[12];
    const float* wih1  = (const float*)d_in[13];
    const float* whh1  = (const float*)d_in[14];
    const float* b1    = (const float*)d_in[15];
    const float* crfW  = (const float*)d_in[16];
    const float* crfB  = (const float*)d_in[17];
    const float* crfT  = (const float*)d_in[18];
    float* outp = (float*)d_out;

    char* ws = (char*)d_ws;
    size_t off = 0;
    auto alloc = [&](size_t bytes) {
        void* p = ws + off;
        off = (off + bytes + 255) & ~(size_t)255;
        return p;
    };
    unsigned short* inp_bf = (unsigned short*)alloc((size_t)4096 * 512 * 2);
    float* xs     = (float*)alloc((size_t)4096 * 2048 * 4);
    float* out0   = (float*)alloc((size_t)4096 * 512 * 4);
    float* out1   = (float*)alloc((size_t)4096 * 512 * 4);
    unsigned short* outb0 = (unsigned short*)alloc((size_t)4096 * 512 * 2);
    unsigned short* outb1 = (unsigned short*)alloc((size_t)4096 * 512 * 2);
    float* em     = (float*)alloc((size_t)4096 * 48 * 4);
    uint4* Wp0    = (uint4*)alloc((size_t)2 * 64 * 256 * 16);
    uint4* Wp1    = (uint4*)alloc((size_t)2 * 64 * 256 * 16);
    unsigned short* wbf0 = (unsigned short*)alloc((size_t)2048 * 512 * 2);
    unsigned short* wbf1 = (unsigned short*)alloc((size_t)2048 * 512 * 2);
    float* crfBT  = (float*)alloc((size_t)48 * 512 * 4);
    float* convWT = (float*)alloc((size_t)30000 * 4);

    const int miscN = 2 * 2048 * 512 + 48 * 512 + 30000;
    prep_misc<<<(miscN + 255) / 256, 256, 0, stream>>>(wih0, wih1, crfW, convW,
                                                       wbf0, wbf1, crfBT, convWT, outp);
    prep_whh<<<64, 256, 0, stream>>>(whh0, whh1, Wp0, Wp1);
    embed_conv<<<4096, 256, 0, stream>>>(iv, ov, ch, emb, ooevT, ctab, convWT, convB, inp_bf);
    gemm_bf16<<<dim3(16, 32), 256, 0, stream>>>(inp_bf, wbf0, b0, xs, 2048);
    lstm_rec<<<64, 1024, 0, stream>>>(xs, Wp0, mask, out0, outb0);
    gemm_bf16<<<dim3(16, 32), 256, 0, stream>>>(outb0, wbf1, b1, xs, 2048);
    lstm_rec<<<64, 1024, 0, stream>>>(xs, Wp1, mask, out1, outb1);
    gemm_bt<<<dim3(1, 32), 256, 0, stream>>>(out1, crfBT, crfB, em, 4096, 48, 512);
    crf_loss<<<8, 192, 0, stream>>>(em, crfT, tgt, mask, outp);
}